// Round 16
// baseline (213.170 us; speedup 1.0000x reference)
//
#include <hip/hip_runtime.h>
#include <hip/hip_bf16.h>
#include <stdint.h>

// Problem constants
#define Bx  4
#define Sx  2048
#define Dx  1024
#define Hx  16
#define DHx 64
#define Mx  (Bx*Sx)   // 8192

typedef short bf16x8 __attribute__((ext_vector_type(8)));
typedef float f32x4  __attribute__((ext_vector_type(4)));
typedef float f32x16 __attribute__((ext_vector_type(16)));

#define C1 0.18033688f   // 0.125 * log2(e)

__device__ __forceinline__ unsigned short f2bf_u(float f) {
  union { float f; unsigned int u; } c; c.f = f;
  return (unsigned short)((c.u + 0x7fffu + ((c.u >> 16) & 1u)) >> 16);
}
__device__ __forceinline__ unsigned int pack2(float lo, float hi) {
  return ((unsigned int)f2bf_u(hi) << 16) | (unsigned int)f2bf_u(lo);
}
// packed f32->bf16 (RNE), lo -> bits[15:0], hi -> bits[31:16]
__device__ __forceinline__ unsigned int cvtpk(float lo_, float hi_) {
  unsigned int r;
  asm("v_cvt_pk_bf16_f32 %0, %1, %2" : "=v"(r) : "v"(lo_), "v"(hi_));
  return r;
}
// swap low 32 lanes of d with high 32 lanes of s
__device__ __forceinline__ void swap32(unsigned int& d, unsigned int& s) {
  asm("v_permlane32_swap_b32 %0, %1" : "+v"(d), "+v"(s));
}

#define GLDS16(gp, lp) __builtin_amdgcn_global_load_lds( \
  (const __attribute__((address_space(1))) unsigned int*)(gp), \
  (__attribute__((address_space(3))) unsigned int*)(lp), 16, 0, 0)

// ---------------- fused prep: cvt x + 4 weights, madd, maskbits ----------
// grid layout: [0,4096) x-cvt | [4096,6144) W-cvt (512 blocks each) |
//              [6144,6176) madd | [6176,6180) maskbits
// xb/wb stored CHUNK-SWIZZLED: c ^= P(row), P(row)=(row&3)^((row>>2)&3).
__global__ __launch_bounds__(256) void prep_kernel(
    const float* __restrict__ x,  const float* __restrict__ Wq,
    const float* __restrict__ Wk, const float* __restrict__ Wv,
    const float* __restrict__ Wo, const int* __restrict__ mask,
    uint4* __restrict__ xb4, uint4* __restrict__ wb4,
    float* __restrict__ madd, unsigned* __restrict__ mb) {
  int bid = blockIdx.x, t = threadIdx.x;
  if (bid < 6144) {
    const float* src;
    uint4* dst;
    int i;
    if (bid < 4096) {
      src = x; dst = xb4; i = bid * 256 + t;
    } else {
      int wbid = bid - 4096;          // 0..2047
      int widx = wbid >> 9;           // 0..3
      src = (widx == 0) ? Wq : (widx == 1) ? Wk : (widx == 2) ? Wv : Wo;
      dst = wb4 + (size_t)widx * 131072;
      i = (wbid & 511) * 256 + t;
    }
    const float4* s = (const float4*)src + (size_t)i * 2;
    float4 a = s[0], b = s[1];
    uint4 o;
    o.x = pack2(a.x, a.y); o.y = pack2(a.z, a.w);
    o.z = pack2(b.x, b.y); o.w = pack2(b.z, b.w);
    int ip = (i & ~3) | ((i & 3) ^ ((i >> 7) & 3) ^ ((i >> 9) & 3));
    dst[ip] = o;
  } else if (bid < 6176) {
    int i = (bid - 6144) * 256 + t;   // 0..8191
    madd[i] = (mask[i] == 0) ? -1e30f : 0.0f;
  } else {
    int b = bid - 6176;               // 0..3
    if (t < 64) {
      int any = 0;
      if (t < 32) {
        for (int i = 0; i < 64; ++i) any |= (mask[b * Sx + t * 64 + i] == 0);
      }
      unsigned long long bits = __ballot(any != 0);
      if (t == 0) mb[b] = (unsigned)bits;
    }
  }
}

// ---------------- QKV GEMM: y = x @ W^T + b (one matrix per launch) ----
// 128x128 tile, BK=32, 4 waves, SERIAL global_load_lds staging (2-phase
// NEGATIVE twice: R8 w/setprio, R15 clean; BK=64 NEGATIVE twice: R6/R11).
// Launched 3x (which=0,1,2) so each launch's per-XCD working set is
// x-chunk 2MB + W_which 2MB = 4MB -> L2-resident (the proven proj regime;
// single-launch all-3 ran at 8MB/XCD -> HBM-latency-bound, 83us - R14).
// XCD-aware swizzle: xcd = lid&7 owns m_tiles [xcd*8, xcd*8+8) x all n.
// Fragment reads XOR chunk with pl=(fr&3)^((fr>>2)&3) (prep layout).
// Output layouts (per head, head base = (b*16+h)*S*64):
//  Q: normal [B,H,S,DH], PRE-SCALED by C1 (log2-domain scores)
//  K: tile-linear swizzled: elem (s,dh) at s*64 + (((dh>>3)^(s&7))<<3) + (dh&7)
//  V: transposed tile-linear swizzled (tiles of 64 s):
//     elem (s,dh) at (s>>6)*4096 + dh*64 + ((((s>>3)&7)^(dh&7))<<3) + (s&7)
__global__ __launch_bounds__(256) void qkv_gemm(
    const short* __restrict__ xb, const short* __restrict__ wb,
    const float* __restrict__ bq, const float* __restrict__ bk,
    const float* __restrict__ bv,
    short* __restrict__ qb, short* __restrict__ kb, short* __restrict__ vb,
    int which) {
  // linear wg id (grid = dim3(8,64)); xcd = lid&7 by dispatch round-robin
  int lid = blockIdx.x + (blockIdx.y << 3);
  int xcd = lid & 7;
  int tt = lid >> 3;           // 0..63
  int m0 = (xcd * 8 + (tt >> 3)) * 128;
  int n0 = (tt & 7) * 128;

  const short* Wm  = wb + (size_t)which * Dx * Dx;
  const float* bias = (which == 0) ? bq : (which == 1 ? bk : bv);

  // main loop uses first 8192 shorts (Al 4096 | Bl 4096);
  // V epilogue reuses all 128*136 shorts as a transpose buffer.
  __shared__ alignas(16) short smem[128 * 136];
  short* Al = smem;
  short* Bl = smem + 4096;

  int t = threadIdx.x;
  int l = t & 63, w = t >> 6;
  int wm = w >> 1, wn = w & 1;
  int srow = l >> 2;
  int scol = (l & 3) * 8;
  int fr = l & 15, fg = l >> 4;
  int pl = (fr & 3) ^ ((fr >> 2) & 3);     // chunk-XOR (matches prep layout)
  int cA = ((fg ^ pl) << 3);               // per-lane constant read chunk

  f32x4 acc[4][4] = {};

  for (int k0 = 0; k0 < Dx; k0 += 32) {
#pragma unroll
    for (int i = 0; i < 2; ++i) {
      int r0 = (w * 2 + i) * 16;
      const short* ga = xb + (size_t)(m0 + r0 + srow) * Dx + k0 + scol;
      GLDS16(ga, &Al[r0 * 32]);
      const short* gb = Wm + (size_t)(n0 + r0 + srow) * Dx + k0 + scol;
      GLDS16(gb, &Bl[r0 * 32]);
    }
    __syncthreads();
    bf16x8 af[4], bfm[4];
#pragma unroll
    for (int i = 0; i < 4; ++i)
      af[i] = *(const bf16x8*)&Al[(wm * 64 + i * 16 + fr) * 32 + cA];
#pragma unroll
    for (int i = 0; i < 4; ++i)
      bfm[i] = *(const bf16x8*)&Bl[(wn * 64 + i * 16 + fr) * 32 + cA];
#pragma unroll
    for (int mi = 0; mi < 4; ++mi)
#pragma unroll
      for (int ni = 0; ni < 4; ++ni)
        acc[mi][ni] = __builtin_amdgcn_mfma_f32_16x16x32_bf16(
            af[mi], bfm[ni], acc[mi][ni], 0, 0, 0);
    __syncthreads();
  }

  if (which == 2) {
    // ---- V epilogue: bias, transpose via LDS, coalesced swizzled store ----
#pragma unroll
    for (int ni = 0; ni < 4; ++ni) {
      int n_l = wn * 64 + ni * 16 + fr;
      float bias_n = bias[n0 + n_l];
#pragma unroll
      for (int mi = 0; mi < 4; ++mi)
#pragma unroll
        for (int r = 0; r < 4; ++r) {
          int m_l = wm * 64 + mi * 16 + fg * 4 + r;
          smem[n_l * 136 + m_l] = (short)f2bf_u(acc[mi][ni][r] + bias_n);
        }
    }
    __syncthreads();
    int b = m0 >> 11, s0_ = m0 & 2047;   // s0_ multiple of 128
#pragma unroll
    for (int it = 0; it < 8; ++it) {
      int idx2 = t + it * 256;          // 0..2047
      int n_l = idx2 >> 4, c = idx2 & 15;
      int4 v = *(const int4*)&smem[n_l * 136 + c * 8];
      int n = n0 + n_l, h = n >> 6, dh = n & 63;
      int chunk = (c & 7) ^ (dh & 7);
      size_t off = (size_t)(b * Hx + h) * Sx * 64
                 + (size_t)((s0_ >> 6) + (c >> 3)) * 4096
                 + dh * 64 + chunk * 8;
      *(int4*)&vb[off] = v;
    }
    return;
  }

#pragma unroll
  for (int ni = 0; ni < 4; ++ni) {
    int n = n0 + wn * 64 + ni * 16 + fr;
    int h = n >> 6, dh = n & 63;
    float bias_n = bias[n];
#pragma unroll
    for (int mi = 0; mi < 4; ++mi) {
#pragma unroll
      for (int r = 0; r < 4; ++r) {
        int m = m0 + wm * 64 + mi * 16 + fg * 4 + r;
        int b = m >> 11, s = m & 2047;
        float y = acc[mi][ni][r] + bias_n;
        size_t hb = (size_t)(b * Hx + h) * Sx * DHx;
        if (which == 0) {
          qb[hb + (size_t)s * DHx + dh] = (short)f2bf_u(y * C1);
        } else {
          kb[hb + (size_t)s * 64 + ((((dh >> 3) ^ (s & 7)) << 3) | (dh & 7))] =
              (short)f2bf_u(y);
        }
      }
    }
  }
}

// ---------------- Flash attention, swapped-QK 32x32, fixed-scale softmax ----
// grid: (bh=64, qt=8). block: 256 = 4 waves; wave owns 64 query rows as TWO
// 32-row groups (A/B) sharing every K/V LDS fragment read - halves LDS-pipe
// read traffic per q-row. KV tile = 64, double-buffered staging with counted
// vmcnt(4). VGPR ~240, __launch_bounds__(256,2). The ctx write applies the
// chunk-XOR P(row) so cb matches the GEMM pre-swizzled A-operand layout.
__global__ __launch_bounds__(256, 2) void attn_kernel(
    const short* __restrict__ qb, const short* __restrict__ kb,
    const short* __restrict__ vb, const float* __restrict__ madd,
    const unsigned* __restrict__ maskbits, short* __restrict__ cbuf) {
  int bh = blockIdx.x;   // 0..63 -> XCD = bh&7
  int qt = blockIdx.y;   // 0..7
  int b  = bh >> 4;

  __shared__ alignas(16) short Kl[2][4096];   // [64 s][64 dh] swizzled
  __shared__ alignas(16) short Vt[2][4096];   // [64 dh][64 s] swizzled

  int t = threadIdx.x, l = t & 63, w = t >> 6;
  int lo = l & 31, hi = l >> 5;

  // Q fragments (B-operand) for both q-groups: lane holds Q[q0+lo][...]
  const short* qgA = qb + ((size_t)bh * Sx + qt * 256 + w * 64 + lo) * 64;
  const short* qgB = qgA + 32 * 64;
  bf16x8 qfA[4], qfB[4];
#pragma unroll
  for (int ks = 0; ks < 4; ++ks) {
    qfA[ks] = *(const bf16x8*)&qgA[ks * 16 + hi * 8];
    qfB[ks] = *(const bf16x8*)&qgB[ks * 16 + hi * 8];
  }

  // Loop-invariant per-lane LDS fragment offsets (shorts). Same formula
  // serves K (QK phase) and V (PV phase).
  int koff[4], koff32[4];
#pragma unroll
  for (int ks = 0; ks < 4; ++ks) {
    int c = ((2 * ks + hi) ^ (lo & 7)) << 3;
    koff[ks]   = lo * 64 + c;
    koff32[ks] = (32 + lo) * 64 + c;
  }

  const short* kg = kb + (size_t)bh * Sx * 64;
  const short* vg = vb + (size_t)bh * Sx * 64;
  const float* mg = madd + b * Sx;
  unsigned mbits = maskbits[b];

  bf16x8 ones;
#pragma unroll
  for (int i = 0; i < 8; ++i) ones[i] = (short)0x3F80;

  f32x16 OA0 = {}, OA1 = {}, SsA = {};
  f32x16 OB0 = {}, OB1 = {}, SsB = {};

#define STAGE(tile, bf) do {                                              \
    const short* ks_ = kg + (size_t)(tile) * 4096;                        \
    const short* vs_ = vg + (size_t)(tile) * 4096;                        \
    GLDS16(ks_ + w * 512 + l * 8,        &Kl[bf][w * 512]);               \
    GLDS16(ks_ + 2048 + w * 512 + l * 8, &Kl[bf][2048 + w * 512]);        \
    GLDS16(vs_ + w * 512 + l * 8,        &Vt[bf][w * 512]);               \
    GLDS16(vs_ + 2048 + w * 512 + l * 8, &Vt[bf][2048 + w * 512]);        \
  } while (0)

#define TBODY(tile, cur) do {                                             \
    if ((tile) < 31) {                                                    \
      STAGE((tile) + 1, (cur) ^ 1);                                       \
      asm volatile("s_waitcnt vmcnt(4)" ::: "memory");                    \
    } else {                                                              \
      asm volatile("s_waitcnt vmcnt(0)" ::: "memory");                    \
    }                                                                     \
    __builtin_amdgcn_s_barrier();                                         \
    const short* Kb = &Kl[cur][0];                                        \
    const short* Vb = &Vt[cur][0];                                        \
    f32x16 sA0 = {}, sA1 = {}, sB0 = {}, sB1 = {};                        \
    __builtin_amdgcn_s_setprio(1);                                        \
    _Pragma("unroll")                                                     \
    for (int ks = 0; ks < 4; ++ks) {                                      \
      bf16x8 kf = *(const bf16x8*)&Kb[koff[ks]];                          \
      sA0 = __builtin_amdgcn_mfma_f32_32x32x16_bf16(kf, qfA[ks], sA0, 0, 0, 0); \
      sB0 = __builtin_amdgcn_mfma_f32_32x32x16_bf16(kf, qfB[ks], sB0, 0, 0, 0); \
    }                                                                     \
    _Pragma("unroll")                                                     \
    for (int ks = 0; ks < 4; ++ks) {                                      \
      bf16x8 kf = *(const bf16x8*)&Kb[koff32[ks]];                        \
      sA1 = __builtin_amdgcn_mfma_f32_32x32x16_bf16(kf, qfA[ks], sA1, 0, 0, 0); \
      sB1 = __builtin_amdgcn_mfma_f32_32x32x16_bf16(kf, qfB[ks], sB1, 0, 0, 0); \
    }                                                                     \
    __builtin_amdgcn_s_setprio(0);                                        \
    if ((mbits >> (tile)) & 1) {                                          \
      const float* mrow = mg + (tile) * 64;                               \
      _Pragma("unroll")                                                   \
      for (int r = 0; r < 16; ++r) {                                      \
        int key = (r & 3) + 8 * (r >> 2) + 4 * hi;                        \
        float m0_ = mrow[key], m1_ = mrow[32 + key];                      \
        sA0[r] += m0_; sA1[r] += m1_;                                     \
        sB0[r] += m0_; sB1[r] += m1_;                                     \
      }                                                                   \
    }                                                                     \
    _Pragma("unroll")                                                     \
    for (int r = 0; r < 16; ++r) {                                        \
      sA0[r] = __builtin_amdgcn_exp2f(sA0[r]);                            \
      sA1[r] = __builtin_amdgcn_exp2f(sA1[r]);                            \
      sB0[r] = __builtin_amdgcn_exp2f(sB0[r]);                            \
      sB1[r] = __builtin_amdgcn_exp2f(sB1[r]);                            \
    }                                                                     \
    __builtin_amdgcn_s_setprio(1);                                        \
    _Pragma("unroll")                                                     \
    for (int kbi = 0; kbi < 2; ++kbi) {                                   \
      _Pragma("unroll")                                                   \
      for (int half = 0; half < 2; ++half) {                              \
        int po = half * 8;                                                \
        unsigned int uA, uA2, vA, vA2, uB, uB2, vB, vB2;                  \
        if (kbi == 0) {                                                   \
          uA  = cvtpk(sA0[po + 0], sA0[po + 1]);                          \
          uA2 = cvtpk(sA0[po + 2], sA0[po + 3]);                          \
          vA  = cvtpk(sA0[po + 4], sA0[po + 5]);                          \
          vA2 = cvtpk(sA0[po + 6], sA0[po + 7]);                          \
          uB  = cvtpk(sB0[po + 0], sB0[po + 1]);                          \
          uB2 = cvtpk(sB0[po + 2], sB0[po + 3]);                          \
          vB  = cvtpk(sB0[po + 4], sB0[po + 5]);                          \
          vB2 = cvtpk(sB0[po + 6], sB0[po + 7]);                          \
        } else {                                                          \
          uA  = cvtpk(sA1[po + 0], sA1[po + 1]);                          \
          uA2 = cvtpk(sA1[po + 2], sA1[po + 3]);                          \
          vA  = cvtpk(sA1[po + 4], sA1[po + 5]);                          \
          vA2 = cvtpk(sA1[po + 6], sA1[po + 7]);                          \
          uB  = cvtpk(sB1[po + 0], sB1[po + 1]);                          \
          uB2 = cvtpk(sB1[po + 2], sB1[po + 3]);                          \
          vB  = cvtpk(sB1[po + 4], sB1[po + 5]);                          \
          vB2 = cvtpk(sB1[po + 6], sB1[po + 7]);                          \
        }                                                                 \
        swap32(vA, uA); swap32(vA2, uA2);                                 \
        swap32(vB, uB); swap32(vB2, uB2);                                 \
        union { unsigned int i[4]; bf16x8 v8; } puA, puB;                 \
        puA.i[0] = uA; puA.i[1] = uA2; puA.i[2] = vA; puA.i[3] = vA2;     \
        puB.i[0] = uB; puB.i[1] = uB2; puB.i[2] = vB; puB.i[3] = vB2;     \
        int vi = kbi * 2 + half;                                          \
        bf16x8 vf0 = *(const bf16x8*)&Vb[koff[vi]];                       \
        bf16x8 vf1 = *(const bf16x8*)&Vb[koff32[vi]];                     \
        OA0 = __builtin_amdgcn_mfma_f32_32x32x16_bf16(puA.v8, vf0, OA0, 0, 0, 0); \
        OA1 = __builtin_amdgcn_mfma_f32_32x32x16_bf16(puA.v8, vf1, OA1, 0, 0, 0); \
        SsA = __builtin_amdgcn_mfma_f32_32x32x16_bf16(puA.v8, ones, SsA, 0, 0, 0); \
        OB0 = __builtin_amdgcn_mfma_f32_32x32x16_bf16(puB.v8, vf0, OB0, 0, 0, 0); \
        OB1 = __builtin_amdgcn_mfma_f32_32x32x16_bf16(puB.v8, vf1, OB1, 0, 0, 0); \
        SsB = __builtin_amdgcn_mfma_f32_32x32x16_bf16(puB.v8, ones, SsB, 0, 0, 0); \
      }                                                                   \
    }                                                                     \
    __builtin_amdgcn_s_setprio(0);                                        \
    __builtin_amdgcn_s_barrier();                                        \
  } while (0)

  STAGE(0, 0);

  for (int tile = 0; tile < 32; tile += 2) {
    TBODY(tile, 0);
    TBODY(tile + 1, 1);
  }
#undef TBODY
#undef STAGE

  // ---- normalize + write ctx (chunk-swizzled cb for proj's A-operand) ----
  int h = bh & 15, bq_ = bh >> 4;
  int loLo = lo & 7, loCh = lo >> 3;   // chunk/offset of this lane's column
#pragma unroll
  for (int a = 0; a < 4; ++a) {
#pragma unroll
    for (int j = 0; j < 4; ++j) {
      int r = a * 4 + j;
      int srow = a * 8 + hi * 4 + j;
      int p = (srow & 3) ^ ((srow >> 2) & 3);   // P(row); rows sA,sB share it
      int colp = ((loCh ^ p) << 3) | loLo;      // permuted within 32-col block
      float linvA = __builtin_amdgcn_rcpf(SsA[r]);
      float linvB = __builtin_amdgcn_rcpf(SsB[r]);
      int sA = qt * 256 + w * 64 + srow;
      int sB = sA + 32;
      size_t rowbA = ((size_t)(bq_ * Sx + sA)) * Dx + h * 64;
      size_t rowbB = ((size_t)(bq_ * Sx + sB)) * Dx + h * 64;
      cbuf[rowbA + colp]      = (short)f2bf_u(OA0[r] * linvA);
      cbuf[rowbA + 32 + colp] = (short)f2bf_u(OA1[r] * linvA);
      cbuf[rowbB + colp]      = (short)f2bf_u(OB0[r] * linvB);
      cbuf[rowbB + 32 + colp] = (short)f2bf_u(OB1[r] * linvB);
    }
  }
}

// ---------------- Output proj GEMM + bias + residual (fp32 out) -----------
// 128x128 tile, BK=32 serial; XCD-aware swizzle; chunk-XOR fragment reads
// match pre-swizzled cb (from attn) and wb (from prep).
__global__ __launch_bounds__(256) void proj_gemm(
    const short* __restrict__ cb, const short* __restrict__ wo,
    const float* __restrict__ bo, const float* __restrict__ x,
    float* __restrict__ out) {
  int lid = blockIdx.x + (blockIdx.y << 3);   // grid = dim3(8,64)
  int xcd = lid & 7;
  int tt = lid >> 3;           // 0..63
  int m0 = (xcd * 8 + (tt >> 3)) * 128;
  int n0 = (tt & 7) * 128;

  __shared__ alignas(16) short Al[128 * 32];
  __shared__ alignas(16) short Bl[128 * 32];

  int t = threadIdx.x;
  int l = t & 63, w = t >> 6;
  int wm = w >> 1, wn = w & 1;
  int srow = l >> 2, scol = (l & 3) * 8;
  int fr = l & 15, fg = l >> 4;
  int pl = (fr & 3) ^ ((fr >> 2) & 3);
  int cA = ((fg ^ pl) << 3);

  f32x4 acc[4][4] = {};

  for (int k0 = 0; k0 < Dx; k0 += 32) {
#pragma unroll
    for (int i = 0; i < 2; ++i) {
      int r0 = (w * 2 + i) * 16;
      const short* ga = cb + (size_t)(m0 + r0 + srow) * Dx + k0 + scol;
      GLDS16(ga, &Al[r0 * 32]);
      const short* gb = wo + (size_t)(n0 + r0 + srow) * Dx + k0 + scol;
      GLDS16(gb, &Bl[r0 * 32]);
    }
    __syncthreads();
    bf16x8 af[4], bfm[4];
#pragma unroll
    for (int i = 0; i < 4; ++i)
      af[i] = *(const bf16x8*)&Al[(wm * 64 + i * 16 + fr) * 32 + cA];
#pragma unroll
    for (int i = 0; i < 4; ++i)
      bfm[i] = *(const bf16x8*)&Bl[(wn * 64 + i * 16 + fr) * 32 + cA];
#pragma unroll
    for (int mi = 0; mi < 4; ++mi)
#pragma unroll
      for (int ni = 0; ni < 4; ++ni)
        acc[mi][ni] = __builtin_amdgcn_mfma_f32_16x16x32_bf16(
            af[mi], bfm[ni], acc[mi][ni], 0, 0, 0);
    __syncthreads();
  }

#pragma unroll
  for (int ni = 0; ni < 4; ++ni) {
    int n = n0 + wn * 64 + ni * 16 + fr;
    float bias_n = bo[n];
#pragma unroll
    for (int mi = 0; mi < 4; ++mi) {
#pragma unroll
      for (int r = 0; r < 4; ++r) {
        int m = m0 + wm * 64 + mi * 16 + fg * 4 + r;
        float y = acc[mi][ni][r] + bias_n + x[(size_t)m * Dx + n];
        out[(size_t)m * Dx + n] = y;
      }
    }
  }
}

// ---------------- LayerNorm (in-place on fp32 rows of 1024) ---------------
__global__ __launch_bounds__(256) void ln_kernel(float* __restrict__ io,
                                                 const float* __restrict__ lw,
                                                 const float* __restrict__ lb) {
  int row = blockIdx.x;
  float* p = io + (size_t)row * Dx;
  int c = threadIdx.x * 4;
  float4 v = *(float4*)&p[c];
  float s = v.x + v.y + v.z + v.w;
  float q = v.x * v.x + v.y * v.y + v.z * v.z + v.w * v.w;
#pragma unroll
  for (int d = 1; d < 64; d <<= 1) {
    s += __shfl_xor(s, d, 64);
    q += __shfl_xor(q, d, 64);
  }
  __shared__ float ss[4], qq[4];
  int l = threadIdx.x & 63, w = threadIdx.x >> 6;
  if (l == 0) { ss[w] = s; qq[w] = q; }
  __syncthreads();
  s = ss[0] + ss[1] + ss[2] + ss[3];
  q = qq[0] + qq[1] + qq[2] + qq[3];
  float mu = s * (1.f / Dx);
  float var = q * (1.f / Dx) - mu * mu;
  float rstd = rsqrtf(var + 1e-5f);
  float4 w4 = *(const float4*)&lw[c];
  float4 b4 = *(const float4*)&lb[c];
  float4 o;
  o.x = (v.x - mu) * rstd * w4.x + b4.x;
  o.y = (v.y - mu) * rstd * w4.y + b4.y;
  o.z = (v.z - mu) * rstd * w4.z + b4.z;
  o.w = (v.w - mu) * rstd * w4.w + b4.w;
  *(float4*)&p[c] = o;
}

// ---------------- launch ----------------
extern "C" void kernel_launch(void* const* d_in, const int* in_sizes, int n_in,
                              void* d_out, int out_size, void* d_ws, size_t ws_size,
                              hipStream_t stream) {
  const float* x   = (const float*)d_in[0];
  const int*   msk = (const int*)d_in[1];
  const float* Wq  = (const float*)d_in[2];
  const float* bq  = (const float*)d_in[3];
  const float* Wk  = (const float*)d_in[4];
  const float* bk  = (const float*)d_in[5];
  const float* Wv  = (const float*)d_in[6];
  const float* bv  = (const float*)d_in[7];
  const float* Wo  = (const float*)d_in[8];
  const float* bo  = (const float*)d_in[9];
  const float* lnw = (const float*)d_in[10];
  const float* lnb = (const float*)d_in[11];
  float* out = (float*)d_out;

  // Workspace layout (88 MB total)
  char* ws = (char*)d_ws;
  short* xb = (short*)(ws);                          // 16 MB  bf16 x (chunk-swz)
  short* wb = (short*)(ws + (size_t)(16 << 20));     //  8 MB  bf16 W (chunk-swz)
  short* qb = (short*)(ws + (size_t)(24 << 20));     // 16 MB  bf16 Q (pre-scaled)
  short* kb = (short*)(ws + (size_t)(40 << 20));     // 16 MB  bf16 K swizzled
  short* vb = (short*)(ws + (size_t)(56 << 20));     // 16 MB  bf16 V^T swizzled
  short* cb = (short*)(ws + (size_t)(72 << 20));     // 16 MB  bf16 ctx (chunk-swz)
  float* madd = out;                        // d_out scratch, overwritten by proj
  unsigned* mbits = (unsigned*)(out + Mx);  // 4 uints after madd

  prep_kernel<<<6180, 256, 0, stream>>>(x, Wq, Wk, Wv, Wo, msk,
                                        (uint4*)xb, (uint4*)wb, madd, mbits);
  qkv_gemm<<<dim3(8, 64), 256, 0, stream>>>(xb, wb, bq, bk, bv, qb, kb, vb, 0);
  qkv_gemm<<<dim3(8, 64), 256, 0, stream>>>(xb, wb, bq, bk, bv, qb, kb, vb, 1);
  qkv_gemm<<<dim3(8, 64), 256, 0, stream>>>(xb, wb, bq, bk, bv, qb, kb, vb, 2);
  attn_kernel<<<dim3(64, 8), 256, 0, stream>>>(qb, kb, vb, madd, mbits, cb);
  proj_gemm<<<dim3(8, 64), 256, 0, stream>>>(cb, wb + 3 * (size_t)(Dx * Dx), bo, x, out);
  ln_kernel<<<Mx, 256, 0, stream>>>(out, lnw, lnb);
}

// Round 17
// 206.550 us; speedup vs baseline: 1.0321x; 1.0321x over previous
//
#include <hip/hip_runtime.h>
#include <hip/hip_bf16.h>
#include <stdint.h>

// Problem constants
#define Bx  4
#define Sx  2048
#define Dx  1024
#define Hx  16
#define DHx 64
#define Mx  (Bx*Sx)   // 8192

typedef short bf16x8 __attribute__((ext_vector_type(8)));
typedef float f32x4  __attribute__((ext_vector_type(4)));
typedef float f32x16 __attribute__((ext_vector_type(16)));

#define C1 0.18033688f   // 0.125 * log2(e)

__device__ __forceinline__ unsigned short f2bf_u(float f) {
  union { float f; unsigned int u; } c; c.f = f;
  return (unsigned short)((c.u + 0x7fffu + ((c.u >> 16) & 1u)) >> 16);
}
__device__ __forceinline__ unsigned int pack2(float lo, float hi) {
  return ((unsigned int)f2bf_u(hi) << 16) | (unsigned int)f2bf_u(lo);
}
// packed f32->bf16 (RNE), lo -> bits[15:0], hi -> bits[31:16]
__device__ __forceinline__ unsigned int cvtpk(float lo_, float hi_) {
  unsigned int r;
  asm("v_cvt_pk_bf16_f32 %0, %1, %2" : "=v"(r) : "v"(lo_), "v"(hi_));
  return r;
}
// swap low 32 lanes of d with high 32 lanes of s
__device__ __forceinline__ void swap32(unsigned int& d, unsigned int& s) {
  asm("v_permlane32_swap_b32 %0, %1" : "+v"(d), "+v"(s));
}

#define GLDS16(gp, lp) __builtin_amdgcn_global_load_lds( \
  (const __attribute__((address_space(1))) unsigned int*)(gp), \
  (__attribute__((address_space(3))) unsigned int*)(lp), 16, 0, 0)

// ---------------- fused prep: cvt x + 4 weights, madd, maskbits ----------
// grid layout: [0,4096) x-cvt | [4096,6144) W-cvt (512 blocks each) |
//              [6144,6176) madd | [6176,6180) maskbits
// xb/wb stored CHUNK-SWIZZLED: c ^= P(row), P(row)=(row&3)^((row>>2)&3).
__global__ __launch_bounds__(256) void prep_kernel(
    const float* __restrict__ x,  const float* __restrict__ Wq,
    const float* __restrict__ Wk, const float* __restrict__ Wv,
    const float* __restrict__ Wo, const int* __restrict__ mask,
    uint4* __restrict__ xb4, uint4* __restrict__ wb4,
    float* __restrict__ madd, unsigned* __restrict__ mb) {
  int bid = blockIdx.x, t = threadIdx.x;
  if (bid < 6144) {
    const float* src;
    uint4* dst;
    int i;
    if (bid < 4096) {
      src = x; dst = xb4; i = bid * 256 + t;
    } else {
      int wbid = bid - 4096;          // 0..2047
      int widx = wbid >> 9;           // 0..3
      src = (widx == 0) ? Wq : (widx == 1) ? Wk : (widx == 2) ? Wv : Wo;
      dst = wb4 + (size_t)widx * 131072;
      i = (wbid & 511) * 256 + t;
    }
    const float4* s = (const float4*)src + (size_t)i * 2;
    float4 a = s[0], b = s[1];
    uint4 o;
    o.x = pack2(a.x, a.y); o.y = pack2(a.z, a.w);
    o.z = pack2(b.x, b.y); o.w = pack2(b.z, b.w);
    int ip = (i & ~3) | ((i & 3) ^ ((i >> 7) & 3) ^ ((i >> 9) & 3));
    dst[ip] = o;
  } else if (bid < 6176) {
    int i = (bid - 6144) * 256 + t;   // 0..8191
    madd[i] = (mask[i] == 0) ? -1e30f : 0.0f;
  } else {
    int b = bid - 6176;               // 0..3
    if (t < 64) {
      int any = 0;
      if (t < 32) {
        for (int i = 0; i < 64; ++i) any |= (mask[b * Sx + t * 64 + i] == 0);
      }
      unsigned long long bits = __ballot(any != 0);
      if (t == 0) mb[b] = (unsigned)bits;
    }
  }
}

// ---------------- QKV GEMM: y = x @ W^T + b ----
// 128x128 tile, BK=32, 4 waves, SERIAL global_load_lds staging.
// CLOSED negative attempts: 2-phase (R8 w/setprio, R15 clean), BK=64
// (R6, R11), per-matrix launch split (R16). This serial single-launch
// form is the measured optimum for this GEMM.
// XCD-aware swizzle: xcd = lid&7 owns m_tiles [xcd*8, xcd*8+8) x all n, per z.
// Fragment reads XOR chunk with pl=(fr&3)^((fr>>2)&3) (prep layout).
// Output layouts (per head, head base = (b*16+h)*S*64):
//  Q: normal [B,H,S,DH], PRE-SCALED by C1 (log2-domain scores)
//  K: tile-linear swizzled: elem (s,dh) at s*64 + (((dh>>3)^(s&7))<<3) + (dh&7)
//  V: transposed tile-linear swizzled (tiles of 64 s):
//     elem (s,dh) at (s>>6)*4096 + dh*64 + ((((s>>3)&7)^(dh&7))<<3) + (s&7)
__global__ __launch_bounds__(256) void qkv_gemm(
    const short* __restrict__ xb, const short* __restrict__ wb,
    const float* __restrict__ bq, const float* __restrict__ bk,
    const float* __restrict__ bv,
    short* __restrict__ qb, short* __restrict__ kb, short* __restrict__ vb) {
  // linear wg id (grid = dim3(8,64,3)); xcd = lid&7 by dispatch round-robin
  int lid = blockIdx.x + (blockIdx.y << 3) + (blockIdx.z << 9);
  int xcd = lid & 7;
  int idx = lid >> 3;          // 0..191
  int which = idx >> 6;        // 0..2
  int tt = idx & 63;           // 0..63
  int m0 = (xcd * 8 + (tt >> 3)) * 128;
  int n0 = (tt & 7) * 128;

  const short* Wm  = wb + (size_t)which * Dx * Dx;
  const float* bias = (which == 0) ? bq : (which == 1 ? bk : bv);

  // main loop uses first 8192 shorts (Al 4096 | Bl 4096);
  // V epilogue reuses all 128*136 shorts as a transpose buffer.
  __shared__ alignas(16) short smem[128 * 136];
  short* Al = smem;
  short* Bl = smem + 4096;

  int t = threadIdx.x;
  int l = t & 63, w = t >> 6;
  int wm = w >> 1, wn = w & 1;
  int srow = l >> 2;
  int scol = (l & 3) * 8;
  int fr = l & 15, fg = l >> 4;
  int pl = (fr & 3) ^ ((fr >> 2) & 3);     // chunk-XOR (matches prep layout)
  int cA = ((fg ^ pl) << 3);               // per-lane constant read chunk

  f32x4 acc[4][4] = {};

  for (int k0 = 0; k0 < Dx; k0 += 32) {
#pragma unroll
    for (int i = 0; i < 2; ++i) {
      int r0 = (w * 2 + i) * 16;
      const short* ga = xb + (size_t)(m0 + r0 + srow) * Dx + k0 + scol;
      GLDS16(ga, &Al[r0 * 32]);
      const short* gb = Wm + (size_t)(n0 + r0 + srow) * Dx + k0 + scol;
      GLDS16(gb, &Bl[r0 * 32]);
    }
    __syncthreads();
    bf16x8 af[4], bfm[4];
#pragma unroll
    for (int i = 0; i < 4; ++i)
      af[i] = *(const bf16x8*)&Al[(wm * 64 + i * 16 + fr) * 32 + cA];
#pragma unroll
    for (int i = 0; i < 4; ++i)
      bfm[i] = *(const bf16x8*)&Bl[(wn * 64 + i * 16 + fr) * 32 + cA];
#pragma unroll
    for (int mi = 0; mi < 4; ++mi)
#pragma unroll
      for (int ni = 0; ni < 4; ++ni)
        acc[mi][ni] = __builtin_amdgcn_mfma_f32_16x16x32_bf16(
            af[mi], bfm[ni], acc[mi][ni], 0, 0, 0);
    __syncthreads();
  }

  if (which == 2) {
    // ---- V epilogue: bias, transpose via LDS, coalesced swizzled store ----
#pragma unroll
    for (int ni = 0; ni < 4; ++ni) {
      int n_l = wn * 64 + ni * 16 + fr;
      float bias_n = bias[n0 + n_l];
#pragma unroll
      for (int mi = 0; mi < 4; ++mi)
#pragma unroll
        for (int r = 0; r < 4; ++r) {
          int m_l = wm * 64 + mi * 16 + fg * 4 + r;
          smem[n_l * 136 + m_l] = (short)f2bf_u(acc[mi][ni][r] + bias_n);
        }
    }
    __syncthreads();
    int b = m0 >> 11, s0_ = m0 & 2047;   // s0_ multiple of 128
#pragma unroll
    for (int it = 0; it < 8; ++it) {
      int idx2 = t + it * 256;          // 0..2047
      int n_l = idx2 >> 4, c = idx2 & 15;
      int4 v = *(const int4*)&smem[n_l * 136 + c * 8];
      int n = n0 + n_l, h = n >> 6, dh = n & 63;
      int chunk = (c & 7) ^ (dh & 7);
      size_t off = (size_t)(b * Hx + h) * Sx * 64
                 + (size_t)((s0_ >> 6) + (c >> 3)) * 4096
                 + dh * 64 + chunk * 8;
      *(int4*)&vb[off] = v;
    }
    return;
  }

#pragma unroll
  for (int ni = 0; ni < 4; ++ni) {
    int n = n0 + wn * 64 + ni * 16 + fr;
    int h = n >> 6, dh = n & 63;
    float bias_n = bias[n];
#pragma unroll
    for (int mi = 0; mi < 4; ++mi) {
#pragma unroll
      for (int r = 0; r < 4; ++r) {
        int m = m0 + wm * 64 + mi * 16 + fg * 4 + r;
        int b = m >> 11, s = m & 2047;
        float y = acc[mi][ni][r] + bias_n;
        size_t hb = (size_t)(b * Hx + h) * Sx * DHx;
        if (which == 0) {
          qb[hb + (size_t)s * DHx + dh] = (short)f2bf_u(y * C1);
        } else {
          kb[hb + (size_t)s * 64 + ((((dh >> 3) ^ (s & 7)) << 3) | (dh & 7))] =
              (short)f2bf_u(y);
        }
      }
    }
  }
}

// ---------------- Flash attention, swapped-QK 32x32, fixed-scale softmax ----
// grid: (bh=64, qt=8). block: 256 = 4 waves; wave owns 64 query rows as TWO
// 32-row groups (A/B) sharing every K/V LDS fragment read - halves LDS-pipe
// read traffic per q-row. KV tile = 64, double-buffered staging with counted
// vmcnt(4). __launch_bounds__(256,2). The ctx write applies the chunk-XOR
// P(row) so cb matches the GEMM pre-swizzled A-operand layout.
__global__ __launch_bounds__(256, 2) void attn_kernel(
    const short* __restrict__ qb, const short* __restrict__ kb,
    const short* __restrict__ vb, const float* __restrict__ madd,
    const unsigned* __restrict__ maskbits, short* __restrict__ cbuf) {
  int bh = blockIdx.x;   // 0..63 -> XCD = bh&7
  int qt = blockIdx.y;   // 0..7
  int b  = bh >> 4;

  __shared__ alignas(16) short Kl[2][4096];   // [64 s][64 dh] swizzled
  __shared__ alignas(16) short Vt[2][4096];   // [64 dh][64 s] swizzled

  int t = threadIdx.x, l = t & 63, w = t >> 6;
  int lo = l & 31, hi = l >> 5;

  // Q fragments (B-operand) for both q-groups: lane holds Q[q0+lo][...]
  const short* qgA = qb + ((size_t)bh * Sx + qt * 256 + w * 64 + lo) * 64;
  const short* qgB = qgA + 32 * 64;
  bf16x8 qfA[4], qfB[4];
#pragma unroll
  for (int ks = 0; ks < 4; ++ks) {
    qfA[ks] = *(const bf16x8*)&qgA[ks * 16 + hi * 8];
    qfB[ks] = *(const bf16x8*)&qgB[ks * 16 + hi * 8];
  }

  // Loop-invariant per-lane LDS fragment offsets (shorts). Same formula
  // serves K (QK phase) and V (PV phase).
  int koff[4], koff32[4];
#pragma unroll
  for (int ks = 0; ks < 4; ++ks) {
    int c = ((2 * ks + hi) ^ (lo & 7)) << 3;
    koff[ks]   = lo * 64 + c;
    koff32[ks] = (32 + lo) * 64 + c;
  }

  const short* kg = kb + (size_t)bh * Sx * 64;
  const short* vg = vb + (size_t)bh * Sx * 64;
  const float* mg = madd + b * Sx;
  unsigned mbits = maskbits[b];

  bf16x8 ones;
#pragma unroll
  for (int i = 0; i < 8; ++i) ones[i] = (short)0x3F80;

  f32x16 OA0 = {}, OA1 = {}, SsA = {};
  f32x16 OB0 = {}, OB1 = {}, SsB = {};

#define STAGE(tile, bf) do {                                              \
    const short* ks_ = kg + (size_t)(tile) * 4096;                        \
    const short* vs_ = vg + (size_t)(tile) * 4096;                        \
    GLDS16(ks_ + w * 512 + l * 8,        &Kl[bf][w * 512]);               \
    GLDS16(ks_ + 2048 + w * 512 + l * 8, &Kl[bf][2048 + w * 512]);        \
    GLDS16(vs_ + w * 512 + l * 8,        &Vt[bf][w * 512]);               \
    GLDS16(vs_ + 2048 + w * 512 + l * 8, &Vt[bf][2048 + w * 512]);        \
  } while (0)

#define TBODY(tile, cur) do {                                             \
    if ((tile) < 31) {                                                    \
      STAGE((tile) + 1, (cur) ^ 1);                                       \
      asm volatile("s_waitcnt vmcnt(4)" ::: "memory");                    \
    } else {                                                              \
      asm volatile("s_waitcnt vmcnt(0)" ::: "memory");                    \
    }                                                                     \
    __builtin_amdgcn_s_barrier();                                         \
    const short* Kb = &Kl[cur][0];                                        \
    const short* Vb = &Vt[cur][0];                                        \
    f32x16 sA0 = {}, sA1 = {}, sB0 = {}, sB1 = {};                        \
    __builtin_amdgcn_s_setprio(1);                                        \
    _Pragma("unroll")                                                     \
    for (int ks = 0; ks < 4; ++ks) {                                      \
      bf16x8 kf = *(const bf16x8*)&Kb[koff[ks]];                          \
      sA0 = __builtin_amdgcn_mfma_f32_32x32x16_bf16(kf, qfA[ks], sA0, 0, 0, 0); \
      sB0 = __builtin_amdgcn_mfma_f32_32x32x16_bf16(kf, qfB[ks], sB0, 0, 0, 0); \
    }                                                                     \
    _Pragma("unroll")                                                     \
    for (int ks = 0; ks < 4; ++ks) {                                      \
      bf16x8 kf = *(const bf16x8*)&Kb[koff32[ks]];                        \
      sA1 = __builtin_amdgcn_mfma_f32_32x32x16_bf16(kf, qfA[ks], sA1, 0, 0, 0); \
      sB1 = __builtin_amdgcn_mfma_f32_32x32x16_bf16(kf, qfB[ks], sB1, 0, 0, 0); \
    }                                                                     \
    __builtin_amdgcn_s_setprio(0);                                        \
    if ((mbits >> (tile)) & 1) {                                          \
      const float* mrow = mg + (tile) * 64;                               \
      _Pragma("unroll")                                                   \
      for (int r = 0; r < 16; ++r) {                                      \
        int key = (r & 3) + 8 * (r >> 2) + 4 * hi;                        \
        float m0_ = mrow[key], m1_ = mrow[32 + key];                      \
        sA0[r] += m0_; sA1[r] += m1_;                                     \
        sB0[r] += m0_; sB1[r] += m1_;                                     \
      }                                                                   \
    }                                                                     \
    _Pragma("unroll")                                                     \
    for (int r = 0; r < 16; ++r) {                                        \
      sA0[r] = __builtin_amdgcn_exp2f(sA0[r]);                            \
      sA1[r] = __builtin_amdgcn_exp2f(sA1[r]);                            \
      sB0[r] = __builtin_amdgcn_exp2f(sB0[r]);                            \
      sB1[r] = __builtin_amdgcn_exp2f(sB1[r]);                            \
    }                                                                     \
    __builtin_amdgcn_s_setprio(1);                                        \
    _Pragma("unroll")                                                     \
    for (int kbi = 0; kbi < 2; ++kbi) {                                   \
      _Pragma("unroll")                                                   \
      for (int half = 0; half < 2; ++half) {                              \
        int po = half * 8;                                                \
        unsigned int uA, uA2, vA, vA2, uB, uB2, vB, vB2;                  \
        if (kbi == 0) {                                                   \
          uA  = cvtpk(sA0[po + 0], sA0[po + 1]);                          \
          uA2 = cvtpk(sA0[po + 2], sA0[po + 3]);                          \
          vA  = cvtpk(sA0[po + 4], sA0[po + 5]);                          \
          vA2 = cvtpk(sA0[po + 6], sA0[po + 7]);                          \
          uB  = cvtpk(sB0[po + 0], sB0[po + 1]);                          \
          uB2 = cvtpk(sB0[po + 2], sB0[po + 3]);                          \
          vB  = cvtpk(sB0[po + 4], sB0[po + 5]);                          \
          vB2 = cvtpk(sB0[po + 6], sB0[po + 7]);                          \
        } else {                                                          \
          uA  = cvtpk(sA1[po + 0], sA1[po + 1]);                          \
          uA2 = cvtpk(sA1[po + 2], sA1[po + 3]);                          \
          vA  = cvtpk(sA1[po + 4], sA1[po + 5]);                          \
          vA2 = cvtpk(sA1[po + 6], sA1[po + 7]);                          \
          uB  = cvtpk(sB1[po + 0], sB1[po + 1]);                          \
          uB2 = cvtpk(sB1[po + 2], sB1[po + 3]);                          \
          vB  = cvtpk(sB1[po + 4], sB1[po + 5]);                          \
          vB2 = cvtpk(sB1[po + 6], sB1[po + 7]);                          \
        }                                                                 \
        swap32(vA, uA); swap32(vA2, uA2);                                 \
        swap32(vB, uB); swap32(vB2, uB2);                                 \
        union { unsigned int i[4]; bf16x8 v8; } puA, puB;                 \
        puA.i[0] = uA; puA.i[1] = uA2; puA.i[2] = vA; puA.i[3] = vA2;     \
        puB.i[0] = uB; puB.i[1] = uB2; puB.i[2] = vB; puB.i[3] = vB2;     \
        int vi = kbi * 2 + half;                                          \
        bf16x8 vf0 = *(const bf16x8*)&Vb[koff[vi]];                       \
        bf16x8 vf1 = *(const bf16x8*)&Vb[koff32[vi]];                     \
        OA0 = __builtin_amdgcn_mfma_f32_32x32x16_bf16(puA.v8, vf0, OA0, 0, 0, 0); \
        OA1 = __builtin_amdgcn_mfma_f32_32x32x16_bf16(puA.v8, vf1, OA1, 0, 0, 0); \
        SsA = __builtin_amdgcn_mfma_f32_32x32x16_bf16(puA.v8, ones, SsA, 0, 0, 0); \
        OB0 = __builtin_amdgcn_mfma_f32_32x32x16_bf16(puB.v8, vf0, OB0, 0, 0, 0); \
        OB1 = __builtin_amdgcn_mfma_f32_32x32x16_bf16(puB.v8, vf1, OB1, 0, 0, 0); \
        SsB = __builtin_amdgcn_mfma_f32_32x32x16_bf16(puB.v8, ones, SsB, 0, 0, 0); \
      }                                                                   \
    }                                                                     \
    __builtin_amdgcn_s_setprio(0);                                        \
    __builtin_amdgcn_s_barrier();                                        \
  } while (0)

  STAGE(0, 0);

  for (int tile = 0; tile < 32; tile += 2) {
    TBODY(tile, 0);
    TBODY(tile + 1, 1);
  }
#undef TBODY
#undef STAGE

  // ---- normalize + write ctx (chunk-swizzled cb for proj's A-operand) ----
  int h = bh & 15, bq_ = bh >> 4;
  int loLo = lo & 7, loCh = lo >> 3;   // chunk/offset of this lane's column
#pragma unroll
  for (int a = 0; a < 4; ++a) {
#pragma unroll
    for (int j = 0; j < 4; ++j) {
      int r = a * 4 + j;
      int srow = a * 8 + hi * 4 + j;
      int p = (srow & 3) ^ ((srow >> 2) & 3);   // P(row); rows sA,sB share it
      int colp = ((loCh ^ p) << 3) | loLo;      // permuted within 32-col block
      float linvA = __builtin_amdgcn_rcpf(SsA[r]);
      float linvB = __builtin_amdgcn_rcpf(SsB[r]);
      int sA = qt * 256 + w * 64 + srow;
      int sB = sA + 32;
      size_t rowbA = ((size_t)(bq_ * Sx + sA)) * Dx + h * 64;
      size_t rowbB = ((size_t)(bq_ * Sx + sB)) * Dx + h * 64;
      cbuf[rowbA + colp]      = (short)f2bf_u(OA0[r] * linvA);
      cbuf[rowbA + 32 + colp] = (short)f2bf_u(OA1[r] * linvA);
      cbuf[rowbB + colp]      = (short)f2bf_u(OB0[r] * linvB);
      cbuf[rowbB + 32 + colp] = (short)f2bf_u(OB1[r] * linvB);
    }
  }
}

// ---------------- Output proj GEMM + bias + residual (fp32 out) -----------
// 128x128 tile, BK=32 serial; XCD-aware swizzle; chunk-XOR fragment reads
// match pre-swizzled cb (from attn) and wb (from prep).
__global__ __launch_bounds__(256) void proj_gemm(
    const short* __restrict__ cb, const short* __restrict__ wo,
    const float* __restrict__ bo, const float* __restrict__ x,
    float* __restrict__ out) {
  int lid = blockIdx.x + (blockIdx.y << 3);   // grid = dim3(8,64)
  int xcd = lid & 7;
  int tt = lid >> 3;           // 0..63
  int m0 = (xcd * 8 + (tt >> 3)) * 128;
  int n0 = (tt & 7) * 128;

  __shared__ alignas(16) short Al[128 * 32];
  __shared__ alignas(16) short Bl[128 * 32];

  int t = threadIdx.x;
  int l = t & 63, w = t >> 6;
  int wm = w >> 1, wn = w & 1;
  int srow = l >> 2, scol = (l & 3) * 8;
  int fr = l & 15, fg = l >> 4;
  int pl = (fr & 3) ^ ((fr >> 2) & 3);
  int cA = ((fg ^ pl) << 3);

  f32x4 acc[4][4] = {};

  for (int k0 = 0; k0 < Dx; k0 += 32) {
#pragma unroll
    for (int i = 0; i < 2; ++i) {
      int r0 = (w * 2 + i) * 16;
      const short* ga = cb + (size_t)(m0 + r0 + srow) * Dx + k0 + scol;
      GLDS16(ga, &Al[r0 * 32]);
      const short* gb = wo + (size_t)(n0 + r0 + srow) * Dx + k0 + scol;
      GLDS16(gb, &Bl[r0 * 32]);
    }
    __syncthreads();
    bf16x8 af[4], bfm[4];
#pragma unroll
    for (int i = 0; i < 4; ++i)
      af[i] = *(const bf16x8*)&Al[(wm * 64 + i * 16 + fr) * 32 + cA];
#pragma unroll
    for (int i = 0; i < 4; ++i)
      bfm[i] = *(const bf16x8*)&Bl[(wn * 64 + i * 16 + fr) * 32 + cA];
#pragma unroll
    for (int mi = 0; mi < 4; ++mi)
#pragma unroll
      for (int ni = 0; ni < 4; ++ni)
        acc[mi][ni] = __builtin_amdgcn_mfma_f32_16x16x32_bf16(
            af[mi], bfm[ni], acc[mi][ni], 0, 0, 0);
    __syncthreads();
  }

#pragma unroll
  for (int ni = 0; ni < 4; ++ni) {
    int n = n0 + wn * 64 + ni * 16 + fr;
    float bias_n = bo[n];
#pragma unroll
    for (int mi = 0; mi < 4; ++mi) {
#pragma unroll
      for (int r = 0; r < 4; ++r) {
        int m = m0 + wm * 64 + mi * 16 + fg * 4 + r;
        float y = acc[mi][ni][r] + bias_n + x[(size_t)m * Dx + n];
        out[(size_t)m * Dx + n] = y;
      }
    }
  }
}

// ---------------- LayerNorm (in-place on fp32 rows of 1024) ---------------
__global__ __launch_bounds__(256) void ln_kernel(float* __restrict__ io,
                                                 const float* __restrict__ lw,
                                                 const float* __restrict__ lb) {
  int row = blockIdx.x;
  float* p = io + (size_t)row * Dx;
  int c = threadIdx.x * 4;
  float4 v = *(float4*)&p[c];
  float s = v.x + v.y + v.z + v.w;
  float q = v.x * v.x + v.y * v.y + v.z * v.z + v.w * v.w;
#pragma unroll
  for (int d = 1; d < 64; d <<= 1) {
    s += __shfl_xor(s, d, 64);
    q += __shfl_xor(q, d, 64);
  }
  __shared__ float ss[4], qq[4];
  int l = threadIdx.x & 63, w = threadIdx.x >> 6;
  if (l == 0) { ss[w] = s; qq[w] = q; }
  __syncthreads();
  s = ss[0] + ss[1] + ss[2] + ss[3];
  q = qq[0] + qq[1] + qq[2] + qq[3];
  float mu = s * (1.f / Dx);
  float var = q * (1.f / Dx) - mu * mu;
  float rstd = rsqrtf(var + 1e-5f);
  float4 w4 = *(const float4*)&lw[c];
  float4 b4 = *(const float4*)&lb[c];
  float4 o;
  o.x = (v.x - mu) * rstd * w4.x + b4.x;
  o.y = (v.y - mu) * rstd * w4.y + b4.y;
  o.z = (v.z - mu) * rstd * w4.z + b4.z;
  o.w = (v.w - mu) * rstd * w4.w + b4.w;
  *(float4*)&p[c] = o;
}

// ---------------- launch ----------------
extern "C" void kernel_launch(void* const* d_in, const int* in_sizes, int n_in,
                              void* d_out, int out_size, void* d_ws, size_t ws_size,
                              hipStream_t stream) {
  const float* x   = (const float*)d_in[0];
  const int*   msk = (const int*)d_in[1];
  const float* Wq  = (const float*)d_in[2];
  const float* bq  = (const float*)d_in[3];
  const float* Wk  = (const float*)d_in[4];
  const float* bk  = (const float*)d_in[5];
  const float* Wv  = (const float*)d_in[6];
  const float* bv  = (const float*)d_in[7];
  const float* Wo  = (const float*)d_in[8];
  const float* bo  = (const float*)d_in[9];
  const float* lnw = (const float*)d_in[10];
  const float* lnb = (const float*)d_in[11];
  float* out = (float*)d_out;

  // Workspace layout (88 MB total)
  char* ws = (char*)d_ws;
  short* xb = (short*)(ws);                          // 16 MB  bf16 x (chunk-swz)
  short* wb = (short*)(ws + (size_t)(16 << 20));     //  8 MB  bf16 W (chunk-swz)
  short* qb = (short*)(ws + (size_t)(24 << 20));     // 16 MB  bf16 Q (pre-scaled)
  short* kb = (short*)(ws + (size_t)(40 << 20));     // 16 MB  bf16 K swizzled
  short* vb = (short*)(ws + (size_t)(56 << 20));     // 16 MB  bf16 V^T swizzled
  short* cb = (short*)(ws + (size_t)(72 << 20));     // 16 MB  bf16 ctx (chunk-swz)
  float* madd = out;                        // d_out scratch, overwritten by proj
  unsigned* mbits = (unsigned*)(out + Mx);  // 4 uints after madd

  prep_kernel<<<6180, 256, 0, stream>>>(x, Wq, Wk, Wv, Wo, msk,
                                        (uint4*)xb, (uint4*)wb, madd, mbits);
  qkv_gemm<<<dim3(8, 64, 3), 256, 0, stream>>>(xb, wb, bq, bk, bv, qb, kb, vb);
  attn_kernel<<<dim3(64, 8), 256, 0, stream>>>(qb, kb, vb, madd, mbits, cb);
  proj_gemm<<<dim3(8, 64), 256, 0, stream>>>(cb, wb + 3 * (size_t)(Dx * Dx), bo, x, out);
  ln_kernel<<<Mx, 256, 0, stream>>>(out, lnw, lnb);
}

// Round 18
// 202.128 us; speedup vs baseline: 1.0546x; 1.0219x over previous
//
#include <hip/hip_runtime.h>
#include <hip/hip_bf16.h>
#include <stdint.h>

// Problem constants
#define Bx  4
#define Sx  2048
#define Dx  1024
#define Hx  16
#define DHx 64
#define Mx  (Bx*Sx)   // 8192

typedef short bf16x8 __attribute__((ext_vector_type(8)));
typedef float f32x4  __attribute__((ext_vector_type(4)));
typedef float f32x16 __attribute__((ext_vector_type(16)));

#define C1 0.18033688f   // 0.125 * log2(e)

__device__ __forceinline__ unsigned short f2bf_u(float f) {
  union { float f; unsigned int u; } c; c.f = f;
  return (unsigned short)((c.u + 0x7fffu + ((c.u >> 16) & 1u)) >> 16);
}
__device__ __forceinline__ unsigned int pack2(float lo, float hi) {
  return ((unsigned int)f2bf_u(hi) << 16) | (unsigned int)f2bf_u(lo);
}
// packed f32->bf16 (RNE), lo -> bits[15:0], hi -> bits[31:16]
__device__ __forceinline__ unsigned int cvtpk(float lo_, float hi_) {
  unsigned int r;
  asm("v_cvt_pk_bf16_f32 %0, %1, %2" : "=v"(r) : "v"(lo_), "v"(hi_));
  return r;
}
// swap low 32 lanes of d with high 32 lanes of s
__device__ __forceinline__ void swap32(unsigned int& d, unsigned int& s) {
  asm("v_permlane32_swap_b32 %0, %1" : "+v"(d), "+v"(s));
}

#define GLDS16(gp, lp) __builtin_amdgcn_global_load_lds( \
  (const __attribute__((address_space(1))) unsigned int*)(gp), \
  (__attribute__((address_space(3))) unsigned int*)(lp), 16, 0, 0)

// ---------------- fused prep: cvt x + 4 weights, madd, maskbits ----------
// grid layout: [0,4096) x-cvt | [4096,6144) W-cvt (512 blocks each) |
//              [6144,6176) madd | [6176,6180) maskbits
// xb/wb stored CHUNK-SWIZZLED: c ^= P(row), P(row)=(row&3)^((row>>2)&3).
__global__ __launch_bounds__(256) void prep_kernel(
    const float* __restrict__ x,  const float* __restrict__ Wq,
    const float* __restrict__ Wk, const float* __restrict__ Wv,
    const float* __restrict__ Wo, const int* __restrict__ mask,
    uint4* __restrict__ xb4, uint4* __restrict__ wb4,
    float* __restrict__ madd, unsigned* __restrict__ mb) {
  int bid = blockIdx.x, t = threadIdx.x;
  if (bid < 6144) {
    const float* src;
    uint4* dst;
    int i;
    if (bid < 4096) {
      src = x; dst = xb4; i = bid * 256 + t;
    } else {
      int wbid = bid - 4096;          // 0..2047
      int widx = wbid >> 9;           // 0..3
      src = (widx == 0) ? Wq : (widx == 1) ? Wk : (widx == 2) ? Wv : Wo;
      dst = wb4 + (size_t)widx * 131072;
      i = (wbid & 511) * 256 + t;
    }
    const float4* s = (const float4*)src + (size_t)i * 2;
    float4 a = s[0], b = s[1];
    uint4 o;
    o.x = pack2(a.x, a.y); o.y = pack2(a.z, a.w);
    o.z = pack2(b.x, b.y); o.w = pack2(b.z, b.w);
    int ip = (i & ~3) | ((i & 3) ^ ((i >> 7) & 3) ^ ((i >> 9) & 3));
    dst[ip] = o;
  } else if (bid < 6176) {
    int i = (bid - 6144) * 256 + t;   // 0..8191
    madd[i] = (mask[i] == 0) ? -1e30f : 0.0f;
  } else {
    int b = bid - 6176;               // 0..3
    if (t < 64) {
      int any = 0;
      if (t < 32) {
        for (int i = 0; i < 64; ++i) any |= (mask[b * Sx + t * 64 + i] == 0);
      }
      unsigned long long bits = __ballot(any != 0);
      if (t == 0) mb[b] = (unsigned)bits;
    }
  }
}

// ---------------- QKV GEMM: y = x @ W^T + b ----
// 128x128 tile, BK=32, 4 waves. 2-PHASE double-buffered global_load_lds
// staging, attn-style: loop unrolled 2x so the buffer index is COMPILE-TIME
// (R15's failure was runtime bf -> per-step M0/address VALU, VALUBusy 57%);
// per-lane global base pointers hoisted (step*32 offset only); counted
// vmcnt(4); NO setprio (m190). W re-reads are L3-hits (FETCH 49MB << 8x6MB)
// so the hidden latency is ~L3 (~500cyc), fully exposed by the serial loop.
// XCD-aware swizzle: xcd = lid&7 owns m_tiles [xcd*8, xcd*8+8) x all n, per z.
// Fragment reads XOR chunk with pl=(fr&3)^((fr>>2)&3) (prep layout).
// Output layouts (per head, head base = (b*16+h)*S*64):
//  Q: normal [B,H,S,DH], PRE-SCALED by C1 (log2-domain scores)
//  K: tile-linear swizzled: elem (s,dh) at s*64 + (((dh>>3)^(s&7))<<3) + (dh&7)
//  V: transposed tile-linear swizzled (tiles of 64 s):
//     elem (s,dh) at (s>>6)*4096 + dh*64 + ((((s>>3)&7)^(dh&7))<<3) + (s&7)
__global__ __launch_bounds__(256) void qkv_gemm(
    const short* __restrict__ xb, const short* __restrict__ wb,
    const float* __restrict__ bq, const float* __restrict__ bk,
    const float* __restrict__ bv,
    short* __restrict__ qb, short* __restrict__ kb, short* __restrict__ vb) {
  // linear wg id (grid = dim3(8,64,3)); xcd = lid&7 by dispatch round-robin
  int lid = blockIdx.x + (blockIdx.y << 3) + (blockIdx.z << 9);
  int xcd = lid & 7;
  int idx = lid >> 3;          // 0..191
  int which = idx >> 6;        // 0..2
  int tt = idx & 63;           // 0..63
  int m0 = (xcd * 8 + (tt >> 3)) * 128;
  int n0 = (tt & 7) * 128;

  const short* Wm  = wb + (size_t)which * Dx * Dx;
  const float* bias = (which == 0) ? bq : (which == 1 ? bk : bv);

  // dbuf: buf0 = smem[0..8191] (A|B), buf1 = smem[8192..16383];
  // V epilogue reuses all 128*136 shorts as a transpose buffer.
  __shared__ alignas(16) short smem[128 * 136];

  int t = threadIdx.x;
  int l = t & 63, w = t >> 6;
  int wm = w >> 1, wn = w & 1;
  int srow = l >> 2;
  int scol = (l & 3) * 8;
  int fr = l & 15, fg = l >> 4;
  int pl = (fr & 3) ^ ((fr >> 2) & 3);     // chunk-XOR (matches prep layout)
  int cA = ((fg ^ pl) << 3);               // per-lane constant read chunk

  // Hoisted per-lane staging base pointers (k=0); step adds step*32 elems.
  int r0a = (w * 2 + 0) * 16;
  int r0b = (w * 2 + 1) * 16;
  const short* gA0 = xb + (size_t)(m0 + r0a + srow) * Dx + scol;
  const short* gA1 = xb + (size_t)(m0 + r0b + srow) * Dx + scol;
  const short* gB0 = Wm + (size_t)(n0 + r0a + srow) * Dx + scol;
  const short* gB1 = Wm + (size_t)(n0 + r0b + srow) * Dx + scol;

  f32x4 acc[4][4] = {};

#define QSTAGE(step, bf) do {                                             \
    size_t ko = (size_t)(step) * 32;                                      \
    GLDS16(gA0 + ko, &smem[(bf) * 8192 + r0a * 32]);                      \
    GLDS16(gB0 + ko, &smem[(bf) * 8192 + 4096 + r0a * 32]);               \
    GLDS16(gA1 + ko, &smem[(bf) * 8192 + r0b * 32]);                      \
    GLDS16(gB1 + ko, &smem[(bf) * 8192 + 4096 + r0b * 32]);               \
  } while (0)

#define QBODY(step, cur) do {                                             \
    if ((step) < 31) {                                                    \
      QSTAGE((step) + 1, (cur) ^ 1);                                      \
      asm volatile("s_waitcnt vmcnt(4)" ::: "memory");                    \
    } else {                                                              \
      asm volatile("s_waitcnt vmcnt(0)" ::: "memory");                    \
    }                                                                     \
    __builtin_amdgcn_s_barrier();                                         \
    const short* Al = &smem[(cur) * 8192];                                \
    const short* Bl = &smem[(cur) * 8192 + 4096];                         \
    bf16x8 af[4], bfm[4];                                                 \
    _Pragma("unroll")                                                     \
    for (int i = 0; i < 4; ++i)                                           \
      af[i] = *(const bf16x8*)&Al[(wm * 64 + i * 16 + fr) * 32 + cA];     \
    _Pragma("unroll")                                                     \
    for (int i = 0; i < 4; ++i)                                           \
      bfm[i] = *(const bf16x8*)&Bl[(wn * 64 + i * 16 + fr) * 32 + cA];    \
    _Pragma("unroll")                                                     \
    for (int mi = 0; mi < 4; ++mi)                                        \
      _Pragma("unroll")                                                   \
      for (int ni = 0; ni < 4; ++ni)                                      \
        acc[mi][ni] = __builtin_amdgcn_mfma_f32_16x16x32_bf16(            \
            af[mi], bfm[ni], acc[mi][ni], 0, 0, 0);                       \
    __builtin_amdgcn_s_barrier();                                         \
  } while (0)

  QSTAGE(0, 0);

  for (int ks = 0; ks < 32; ks += 2) {
    QBODY(ks, 0);
    QBODY(ks + 1, 1);
  }
#undef QBODY
#undef QSTAGE

  if (which == 2) {
    // ---- V epilogue: bias, transpose via LDS, coalesced swizzled store ----
    __syncthreads();
#pragma unroll
    for (int ni = 0; ni < 4; ++ni) {
      int n_l = wn * 64 + ni * 16 + fr;
      float bias_n = bias[n0 + n_l];
#pragma unroll
      for (int mi = 0; mi < 4; ++mi)
#pragma unroll
        for (int r = 0; r < 4; ++r) {
          int m_l = wm * 64 + mi * 16 + fg * 4 + r;
          smem[n_l * 136 + m_l] = (short)f2bf_u(acc[mi][ni][r] + bias_n);
        }
    }
    __syncthreads();
    int b = m0 >> 11, s0_ = m0 & 2047;   // s0_ multiple of 128
#pragma unroll
    for (int it = 0; it < 8; ++it) {
      int idx2 = t + it * 256;          // 0..2047
      int n_l = idx2 >> 4, c = idx2 & 15;
      int4 v = *(const int4*)&smem[n_l * 136 + c * 8];
      int n = n0 + n_l, h = n >> 6, dh = n & 63;
      int chunk = (c & 7) ^ (dh & 7);
      size_t off = (size_t)(b * Hx + h) * Sx * 64
                 + (size_t)((s0_ >> 6) + (c >> 3)) * 4096
                 + dh * 64 + chunk * 8;
      *(int4*)&vb[off] = v;
    }
    return;
  }

#pragma unroll
  for (int ni = 0; ni < 4; ++ni) {
    int n = n0 + wn * 64 + ni * 16 + fr;
    int h = n >> 6, dh = n & 63;
    float bias_n = bias[n];
#pragma unroll
    for (int mi = 0; mi < 4; ++mi) {
#pragma unroll
      for (int r = 0; r < 4; ++r) {
        int m = m0 + wm * 64 + mi * 16 + fg * 4 + r;
        int b = m >> 11, s = m & 2047;
        float y = acc[mi][ni][r] + bias_n;
        size_t hb = (size_t)(b * Hx + h) * Sx * DHx;
        if (which == 0) {
          qb[hb + (size_t)s * DHx + dh] = (short)f2bf_u(y * C1);
        } else {
          kb[hb + (size_t)s * 64 + ((((dh >> 3) ^ (s & 7)) << 3) | (dh & 7))] =
              (short)f2bf_u(y);
        }
      }
    }
  }
}

// ---------------- Flash attention, swapped-QK 32x32, fixed-scale softmax ----
// grid: (bh=64, qt=8). block: 256 = 4 waves; wave owns 64 query rows as TWO
// 32-row groups (A/B) sharing every K/V LDS fragment read - halves LDS-pipe
// read traffic per q-row. KV tile = 64, double-buffered staging with counted
// vmcnt(4). __launch_bounds__(256,2). The ctx write applies the chunk-XOR
// P(row) so cb matches the GEMM pre-swizzled A-operand layout.
__global__ __launch_bounds__(256, 2) void attn_kernel(
    const short* __restrict__ qb, const short* __restrict__ kb,
    const short* __restrict__ vb, const float* __restrict__ madd,
    const unsigned* __restrict__ maskbits, short* __restrict__ cbuf) {
  int bh = blockIdx.x;   // 0..63 -> XCD = bh&7
  int qt = blockIdx.y;   // 0..7
  int b  = bh >> 4;

  __shared__ alignas(16) short Kl[2][4096];   // [64 s][64 dh] swizzled
  __shared__ alignas(16) short Vt[2][4096];   // [64 dh][64 s] swizzled

  int t = threadIdx.x, l = t & 63, w = t >> 6;
  int lo = l & 31, hi = l >> 5;

  // Q fragments (B-operand) for both q-groups: lane holds Q[q0+lo][...]
  const short* qgA = qb + ((size_t)bh * Sx + qt * 256 + w * 64 + lo) * 64;
  const short* qgB = qgA + 32 * 64;
  bf16x8 qfA[4], qfB[4];
#pragma unroll
  for (int ks = 0; ks < 4; ++ks) {
    qfA[ks] = *(const bf16x8*)&qgA[ks * 16 + hi * 8];
    qfB[ks] = *(const bf16x8*)&qgB[ks * 16 + hi * 8];
  }

  // Loop-invariant per-lane LDS fragment offsets (shorts). Same formula
  // serves K (QK phase) and V (PV phase).
  int koff[4], koff32[4];
#pragma unroll
  for (int ks = 0; ks < 4; ++ks) {
    int c = ((2 * ks + hi) ^ (lo & 7)) << 3;
    koff[ks]   = lo * 64 + c;
    koff32[ks] = (32 + lo) * 64 + c;
  }

  const short* kg = kb + (size_t)bh * Sx * 64;
  const short* vg = vb + (size_t)bh * Sx * 64;
  const float* mg = madd + b * Sx;
  unsigned mbits = maskbits[b];

  bf16x8 ones;
#pragma unroll
  for (int i = 0; i < 8; ++i) ones[i] = (short)0x3F80;

  f32x16 OA0 = {}, OA1 = {}, SsA = {};
  f32x16 OB0 = {}, OB1 = {}, SsB = {};

#define STAGE(tile, bf) do {                                              \
    const short* ks_ = kg + (size_t)(tile) * 4096;                        \
    const short* vs_ = vg + (size_t)(tile) * 4096;                        \
    GLDS16(ks_ + w * 512 + l * 8,        &Kl[bf][w * 512]);               \
    GLDS16(ks_ + 2048 + w * 512 + l * 8, &Kl[bf][2048 + w * 512]);        \
    GLDS16(vs_ + w * 512 + l * 8,        &Vt[bf][w * 512]);               \
    GLDS16(vs_ + 2048 + w * 512 + l * 8, &Vt[bf][2048 + w * 512]);        \
  } while (0)

#define TBODY(tile, cur) do {                                             \
    if ((tile) < 31) {                                                    \
      STAGE((tile) + 1, (cur) ^ 1);                                       \
      asm volatile("s_waitcnt vmcnt(4)" ::: "memory");                    \
    } else {                                                              \
      asm volatile("s_waitcnt vmcnt(0)" ::: "memory");                    \
    }                                                                     \
    __builtin_amdgcn_s_barrier();                                         \
    const short* Kb = &Kl[cur][0];                                        \
    const short* Vb = &Vt[cur][0];                                        \
    f32x16 sA0 = {}, sA1 = {}, sB0 = {}, sB1 = {};                        \
    __builtin_amdgcn_s_setprio(1);                                        \
    _Pragma("unroll")                                                     \
    for (int ks = 0; ks < 4; ++ks) {                                      \
      bf16x8 kf = *(const bf16x8*)&Kb[koff[ks]];                          \
      sA0 = __builtin_amdgcn_mfma_f32_32x32x16_bf16(kf, qfA[ks], sA0, 0, 0, 0); \
      sB0 = __builtin_amdgcn_mfma_f32_32x32x16_bf16(kf, qfB[ks], sB0, 0, 0, 0); \
    }                                                                     \
    _Pragma("unroll")                                                     \
    for (int ks = 0; ks < 4; ++ks) {                                      \
      bf16x8 kf = *(const bf16x8*)&Kb[koff32[ks]];                        \
      sA1 = __builtin_amdgcn_mfma_f32_32x32x16_bf16(kf, qfA[ks], sA1, 0, 0, 0); \
      sB1 = __builtin_amdgcn_mfma_f32_32x32x16_bf16(kf, qfB[ks], sB1, 0, 0, 0); \
    }                                                                     \
    __builtin_amdgcn_s_setprio(0);                                        \
    if ((mbits >> (tile)) & 1) {                                          \
      const float* mrow = mg + (tile) * 64;                               \
      _Pragma("unroll")                                                   \
      for (int r = 0; r < 16; ++r) {                                      \
        int key = (r & 3) + 8 * (r >> 2) + 4 * hi;                        \
        float m0_ = mrow[key], m1_ = mrow[32 + key];                      \
        sA0[r] += m0_; sA1[r] += m1_;                                     \
        sB0[r] += m0_; sB1[r] += m1_;                                     \
      }                                                                   \
    }                                                                     \
    _Pragma("unroll")                                                     \
    for (int r = 0; r < 16; ++r) {                                        \
      sA0[r] = __builtin_amdgcn_exp2f(sA0[r]);                            \
      sA1[r] = __builtin_amdgcn_exp2f(sA1[r]);                            \
      sB0[r] = __builtin_amdgcn_exp2f(sB0[r]);                            \
      sB1[r] = __builtin_amdgcn_exp2f(sB1[r]);                            \
    }                                                                     \
    __builtin_amdgcn_s_setprio(1);                                        \
    _Pragma("unroll")                                                     \
    for (int kbi = 0; kbi < 2; ++kbi) {                                   \
      _Pragma("unroll")                                                   \
      for (int half = 0; half < 2; ++half) {                              \
        int po = half * 8;                                                \
        unsigned int uA, uA2, vA, vA2, uB, uB2, vB, vB2;                  \
        if (kbi == 0) {                                                   \
          uA  = cvtpk(sA0[po + 0], sA0[po + 1]);                          \
          uA2 = cvtpk(sA0[po + 2], sA0[po + 3]);                          \
          vA  = cvtpk(sA0[po + 4], sA0[po + 5]);                          \
          vA2 = cvtpk(sA0[po + 6], sA0[po + 7]);                          \
          uB  = cvtpk(sB0[po + 0], sB0[po + 1]);                          \
          uB2 = cvtpk(sB0[po + 2], sB0[po + 3]);                          \
          vB  = cvtpk(sB0[po + 4], sB0[po + 5]);                          \
          vB2 = cvtpk(sB0[po + 6], sB0[po + 7]);                          \
        } else {                                                          \
          uA  = cvtpk(sA1[po + 0], sA1[po + 1]);                          \
          uA2 = cvtpk(sA1[po + 2], sA1[po + 3]);                          \
          vA  = cvtpk(sA1[po + 4], sA1[po + 5]);                          \
          vA2 = cvtpk(sA1[po + 6], sA1[po + 7]);                          \
          uB  = cvtpk(sB1[po + 0], sB1[po + 1]);                          \
          uB2 = cvtpk(sB1[po + 2], sB1[po + 3]);                          \
          vB  = cvtpk(sB1[po + 4], sB1[po + 5]);                          \
          vB2 = cvtpk(sB1[po + 6], sB1[po + 7]);                          \
        }                                                                 \
        swap32(vA, uA); swap32(vA2, uA2);                                 \
        swap32(vB, uB); swap32(vB2, uB2);                                 \
        union { unsigned int i[4]; bf16x8 v8; } puA, puB;                 \
        puA.i[0] = uA; puA.i[1] = uA2; puA.i[2] = vA; puA.i[3] = vA2;     \
        puB.i[0] = uB; puB.i[1] = uB2; puB.i[2] = vB; puB.i[3] = vB2;     \
        int vi = kbi * 2 + half;                                          \
        bf16x8 vf0 = *(const bf16x8*)&Vb[koff[vi]];                       \
        bf16x8 vf1 = *(const bf16x8*)&Vb[koff32[vi]];                     \
        OA0 = __builtin_amdgcn_mfma_f32_32x32x16_bf16(puA.v8, vf0, OA0, 0, 0, 0); \
        OA1 = __builtin_amdgcn_mfma_f32_32x32x16_bf16(puA.v8, vf1, OA1, 0, 0, 0); \
        SsA = __builtin_amdgcn_mfma_f32_32x32x16_bf16(puA.v8, ones, SsA, 0, 0, 0); \
        OB0 = __builtin_amdgcn_mfma_f32_32x32x16_bf16(puB.v8, vf0, OB0, 0, 0, 0); \
        OB1 = __builtin_amdgcn_mfma_f32_32x32x16_bf16(puB.v8, vf1, OB1, 0, 0, 0); \
        SsB = __builtin_amdgcn_mfma_f32_32x32x16_bf16(puB.v8, ones, SsB, 0, 0, 0); \
      }                                                                   \
    }                                                                     \
    __builtin_amdgcn_s_setprio(0);                                        \
    __builtin_amdgcn_s_barrier();                                        \
  } while (0)

  STAGE(0, 0);

  for (int tile = 0; tile < 32; tile += 2) {
    TBODY(tile, 0);
    TBODY(tile + 1, 1);
  }
#undef TBODY
#undef STAGE

  // ---- normalize + write ctx (chunk-swizzled cb for proj's A-operand) ----
  int h = bh & 15, bq_ = bh >> 4;
  int loLo = lo & 7, loCh = lo >> 3;   // chunk/offset of this lane's column
#pragma unroll
  for (int a = 0; a < 4; ++a) {
#pragma unroll
    for (int j = 0; j < 4; ++j) {
      int r = a * 4 + j;
      int srow = a * 8 + hi * 4 + j;
      int p = (srow & 3) ^ ((srow >> 2) & 3);   // P(row); rows sA,sB share it
      int colp = ((loCh ^ p) << 3) | loLo;      // permuted within 32-col block
      float linvA = __builtin_amdgcn_rcpf(SsA[r]);
      float linvB = __builtin_amdgcn_rcpf(SsB[r]);
      int sA = qt * 256 + w * 64 + srow;
      int sB = sA + 32;
      size_t rowbA = ((size_t)(bq_ * Sx + sA)) * Dx + h * 64;
      size_t rowbB = ((size_t)(bq_ * Sx + sB)) * Dx + h * 64;
      cbuf[rowbA + colp]      = (short)f2bf_u(OA0[r] * linvA);
      cbuf[rowbA + 32 + colp] = (short)f2bf_u(OA1[r] * linvA);
      cbuf[rowbB + colp]      = (short)f2bf_u(OB0[r] * linvB);
      cbuf[rowbB + 32 + colp] = (short)f2bf_u(OB1[r] * linvB);
    }
  }
}

// ---------------- Output proj GEMM + bias + residual (fp32 out) -----------
// 128x128 tile, BK=32 serial; XCD-aware swizzle; chunk-XOR fragment reads
// match pre-swizzled cb (from attn) and wb (from prep).
__global__ __launch_bounds__(256) void proj_gemm(
    const short* __restrict__ cb, const short* __restrict__ wo,
    const float* __restrict__ bo, const float* __restrict__ x,
    float* __restrict__ out) {
  int lid = blockIdx.x + (blockIdx.y << 3);   // grid = dim3(8,64)
  int xcd = lid & 7;
  int tt = lid >> 3;           // 0..63
  int m0 = (xcd * 8 + (tt >> 3)) * 128;
  int n0 = (tt & 7) * 128;

  __shared__ alignas(16) short Al[128 * 32];
  __shared__ alignas(16) short Bl[128 * 32];

  int t = threadIdx.x;
  int l = t & 63, w = t >> 6;
  int wm = w >> 1, wn = w & 1;
  int srow = l >> 2, scol = (l & 3) * 8;
  int fr = l & 15, fg = l >> 4;
  int pl = (fr & 3) ^ ((fr >> 2) & 3);
  int cA = ((fg ^ pl) << 3);

  f32x4 acc[4][4] = {};

  for (int k0 = 0; k0 < Dx; k0 += 32) {
#pragma unroll
    for (int i = 0; i < 2; ++i) {
      int r0 = (w * 2 + i) * 16;
      const short* ga = cb + (size_t)(m0 + r0 + srow) * Dx + k0 + scol;
      GLDS16(ga, &Al[r0 * 32]);
      const short* gb = wo + (size_t)(n0 + r0 + srow) * Dx + k0 + scol;
      GLDS16(gb, &Bl[r0 * 32]);
    }
    __syncthreads();
    bf16x8 af[4], bfm[4];
#pragma unroll
    for (int i = 0; i < 4; ++i)
      af[i] = *(const bf16x8*)&Al[(wm * 64 + i * 16 + fr) * 32 + cA];
#pragma unroll
    for (int i = 0; i < 4; ++i)
      bfm[i] = *(const bf16x8*)&Bl[(wn * 64 + i * 16 + fr) * 32 + cA];
#pragma unroll
    for (int mi = 0; mi < 4; ++mi)
#pragma unroll
      for (int ni = 0; ni < 4; ++ni)
        acc[mi][ni] = __builtin_amdgcn_mfma_f32_16x16x32_bf16(
            af[mi], bfm[ni], acc[mi][ni], 0, 0, 0);
    __syncthreads();
  }

#pragma unroll
  for (int ni = 0; ni < 4; ++ni) {
    int n = n0 + wn * 64 + ni * 16 + fr;
    float bias_n = bo[n];
#pragma unroll
    for (int mi = 0; mi < 4; ++mi) {
#pragma unroll
      for (int r = 0; r < 4; ++r) {
        int m = m0 + wm * 64 + mi * 16 + fg * 4 + r;
        float y = acc[mi][ni][r] + bias_n + x[(size_t)m * Dx + n];
        out[(size_t)m * Dx + n] = y;
      }
    }
  }
}

// ---------------- LayerNorm (in-place on fp32 rows of 1024) ---------------
__global__ __launch_bounds__(256) void ln_kernel(float* __restrict__ io,
                                                 const float* __restrict__ lw,
                                                 const float* __restrict__ lb) {
  int row = blockIdx.x;
  float* p = io + (size_t)row * Dx;
  int c = threadIdx.x * 4;
  float4 v = *(float4*)&p[c];
  float s = v.x + v.y + v.z + v.w;
  float q = v.x * v.x + v.y * v.y + v.z * v.z + v.w * v.w;
#pragma unroll
  for (int d = 1; d < 64; d <<= 1) {
    s += __shfl_xor(s, d, 64);
    q += __shfl_xor(q, d, 64);
  }
  __shared__ float ss[4], qq[4];
  int l = threadIdx.x & 63, w = threadIdx.x >> 6;
  if (l == 0) { ss[w] = s; qq[w] = q; }
  __syncthreads();
  s = ss[0] + ss[1] + ss[2] + ss[3];
  q = qq[0] + qq[1] + qq[2] + qq[3];
  float mu = s * (1.f / Dx);
  float var = q * (1.f / Dx) - mu * mu;
  float rstd = rsqrtf(var + 1e-5f);
  float4 w4 = *(const float4*)&lw[c];
  float4 b4 = *(const float4*)&lb[c];
  float4 o;
  o.x = (v.x - mu) * rstd * w4.x + b4.x;
  o.y = (v.y - mu) * rstd * w4.y + b4.y;
  o.z = (v.z - mu) * rstd * w4.z + b4.z;
  o.w = (v.w - mu) * rstd * w4.w + b4.w;
  *(float4*)&p[c] = o;
}

// ---------------- launch ----------------
extern "C" void kernel_launch(void* const* d_in, const int* in_sizes, int n_in,
                              void* d_out, int out_size, void* d_ws, size_t ws_size,
                              hipStream_t stream) {
  const float* x   = (const float*)d_in[0];
  const int*   msk = (const int*)d_in[1];
  const float* Wq  = (const float*)d_in[2];
  const float* bq  = (const float*)d_in[3];
  const float* Wk  = (const float*)d_in[4];
  const float* bk  = (const float*)d_in[5];
  const float* Wv  = (const float*)d_in[6];
  const float* bv  = (const float*)d_in[7];
  const float* Wo  = (const float*)d_in[8];
  const float* bo  = (const float*)d_in[9];
  const float* lnw = (const float*)d_in[10];
  const float* lnb = (const float*)d_in[11];
  float* out = (float*)d_out;

  // Workspace layout (88 MB total)
  char* ws = (char*)d_ws;
  short* xb = (short*)(ws);                          // 16 MB  bf16 x (chunk-swz)
  short* wb = (short*)(ws + (size_t)(16 << 20));     //  8 MB  bf16 W (chunk-swz)
  short* qb = (short*)(ws + (size_t)(24 << 20));     // 16 MB  bf16 Q (pre-scaled)
  short* kb = (short*)(ws + (size_t)(40 << 20));     // 16 MB  bf16 K swizzled
  short* vb = (short*)(ws + (size_t)(56 << 20));     // 16 MB  bf16 V^T swizzled
  short* cb = (short*)(ws + (size_t)(72 << 20));     // 16 MB  bf16 ctx (chunk-swz)
  float* madd = out;                        // d_out scratch, overwritten by proj
  unsigned* mbits = (unsigned*)(out + Mx);  // 4 uints after madd

  prep_kernel<<<6180, 256, 0, stream>>>(x, Wq, Wk, Wv, Wo, msk,
                                        (uint4*)xb, (uint4*)wb, madd, mbits);
  qkv_gemm<<<dim3(8, 64, 3), 256, 0, stream>>>(xb, wb, bq, bk, bv, qb, kb, vb);
  attn_kernel<<<dim3(64, 8), 256, 0, stream>>>(qb, kb, vb, madd, mbits, cb);
  proj_gemm<<<dim3(8, 64), 256, 0, stream>>>(cb, wb + 3 * (size_t)(Dx * Dx), bo, x, out);
  ln_kernel<<<Mx, 256, 0, stream>>>(out, lnw, lnb);
}

// Round 19
// 201.712 us; speedup vs baseline: 1.0568x; 1.0021x over previous
//
#include <hip/hip_runtime.h>
#include <hip/hip_bf16.h>
#include <stdint.h>

// Problem constants
#define Bx  4
#define Sx  2048
#define Dx  1024
#define Hx  16
#define DHx 64
#define Mx  (Bx*Sx)   // 8192

typedef short bf16x8 __attribute__((ext_vector_type(8)));
typedef float f32x4  __attribute__((ext_vector_type(4)));
typedef float f32x16 __attribute__((ext_vector_type(16)));

#define C1 0.18033688f   // 0.125 * log2(e)

__device__ __forceinline__ unsigned short f2bf_u(float f) {
  union { float f; unsigned int u; } c; c.f = f;
  return (unsigned short)((c.u + 0x7fffu + ((c.u >> 16) & 1u)) >> 16);
}
__device__ __forceinline__ unsigned int pack2(float lo, float hi) {
  return ((unsigned int)f2bf_u(hi) << 16) | (unsigned int)f2bf_u(lo);
}
// packed f32->bf16 (RNE), lo -> bits[15:0], hi -> bits[31:16]
__device__ __forceinline__ unsigned int cvtpk(float lo_, float hi_) {
  unsigned int r;
  asm("v_cvt_pk_bf16_f32 %0, %1, %2" : "=v"(r) : "v"(lo_), "v"(hi_));
  return r;
}
// swap low 32 lanes of d with high 32 lanes of s
__device__ __forceinline__ void swap32(unsigned int& d, unsigned int& s) {
  asm("v_permlane32_swap_b32 %0, %1" : "+v"(d), "+v"(s));
}

#define GLDS16(gp, lp) __builtin_amdgcn_global_load_lds( \
  (const __attribute__((address_space(1))) unsigned int*)(gp), \
  (__attribute__((address_space(3))) unsigned int*)(lp), 16, 0, 0)

// ---------------- fused prep: cvt x + 4 weights, madd, maskbits ----------
// grid layout: [0,4096) x-cvt | [4096,6144) W-cvt (512 blocks each) |
//              [6144,6176) madd | [6176,6180) maskbits
// xb/wb stored CHUNK-SWIZZLED: c ^= P(row), P(row)=(row&3)^((row>>2)&3).
__global__ __launch_bounds__(256) void prep_kernel(
    const float* __restrict__ x,  const float* __restrict__ Wq,
    const float* __restrict__ Wk, const float* __restrict__ Wv,
    const float* __restrict__ Wo, const int* __restrict__ mask,
    uint4* __restrict__ xb4, uint4* __restrict__ wb4,
    float* __restrict__ madd, unsigned* __restrict__ mb) {
  int bid = blockIdx.x, t = threadIdx.x;
  if (bid < 6144) {
    const float* src;
    uint4* dst;
    int i;
    if (bid < 4096) {
      src = x; dst = xb4; i = bid * 256 + t;
    } else {
      int wbid = bid - 4096;          // 0..2047
      int widx = wbid >> 9;           // 0..3
      src = (widx == 0) ? Wq : (widx == 1) ? Wk : (widx == 2) ? Wv : Wo;
      dst = wb4 + (size_t)widx * 131072;
      i = (wbid & 511) * 256 + t;
    }
    const float4* s = (const float4*)src + (size_t)i * 2;
    float4 a = s[0], b = s[1];
    uint4 o;
    o.x = pack2(a.x, a.y); o.y = pack2(a.z, a.w);
    o.z = pack2(b.x, b.y); o.w = pack2(b.z, b.w);
    int ip = (i & ~3) | ((i & 3) ^ ((i >> 7) & 3) ^ ((i >> 9) & 3));
    dst[ip] = o;
  } else if (bid < 6176) {
    int i = (bid - 6144) * 256 + t;   // 0..8191
    madd[i] = (mask[i] == 0) ? -1e30f : 0.0f;
  } else {
    int b = bid - 6176;               // 0..3
    if (t < 64) {
      int any = 0;
      if (t < 32) {
        for (int i = 0; i < 64; ++i) any |= (mask[b * Sx + t * 64 + i] == 0);
      }
      unsigned long long bits = __ballot(any != 0);
      if (t == 0) mb[b] = (unsigned)bits;
    }
  }
}

// ---------------- QKV GEMM: y = x @ W^T + b ----
// 128x128 tile, BK=32, 4 waves. 2-PHASE double-buffered global_load_lds
// staging with COMPILE-TIME buffer index (attn-style 2x unroll; runtime bf
// was R15's failure mode), hoisted per-lane global base pointers, counted
// vmcnt(4), NO setprio. Verified WIN R18: 83 -> 79 us.
// XCD-aware swizzle: xcd = lid&7 owns m_tiles [xcd*8, xcd*8+8) x all n, per z.
// Fragment reads XOR chunk with pl=(fr&3)^((fr>>2)&3) (prep layout).
// Output layouts (per head, head base = (b*16+h)*S*64):
//  Q: normal [B,H,S,DH], PRE-SCALED by C1 (log2-domain scores)
//  K: tile-linear swizzled: elem (s,dh) at s*64 + (((dh>>3)^(s&7))<<3) + (dh&7)
//  V: transposed tile-linear swizzled (tiles of 64 s):
//     elem (s,dh) at (s>>6)*4096 + dh*64 + ((((s>>3)&7)^(dh&7))<<3) + (s&7)
__global__ __launch_bounds__(256) void qkv_gemm(
    const short* __restrict__ xb, const short* __restrict__ wb,
    const float* __restrict__ bq, const float* __restrict__ bk,
    const float* __restrict__ bv,
    short* __restrict__ qb, short* __restrict__ kb, short* __restrict__ vb) {
  // linear wg id (grid = dim3(8,64,3)); xcd = lid&7 by dispatch round-robin
  int lid = blockIdx.x + (blockIdx.y << 3) + (blockIdx.z << 9);
  int xcd = lid & 7;
  int idx = lid >> 3;          // 0..191
  int which = idx >> 6;        // 0..2
  int tt = idx & 63;           // 0..63
  int m0 = (xcd * 8 + (tt >> 3)) * 128;
  int n0 = (tt & 7) * 128;

  const short* Wm  = wb + (size_t)which * Dx * Dx;
  const float* bias = (which == 0) ? bq : (which == 1 ? bk : bv);

  // dbuf: buf0 = smem[0..8191] (A|B), buf1 = smem[8192..16383];
  // V epilogue reuses all 128*136 shorts as a transpose buffer.
  __shared__ alignas(16) short smem[128 * 136];

  int t = threadIdx.x;
  int l = t & 63, w = t >> 6;
  int wm = w >> 1, wn = w & 1;
  int srow = l >> 2;
  int scol = (l & 3) * 8;
  int fr = l & 15, fg = l >> 4;
  int pl = (fr & 3) ^ ((fr >> 2) & 3);     // chunk-XOR (matches prep layout)
  int cA = ((fg ^ pl) << 3);               // per-lane constant read chunk

  // Hoisted per-lane staging base pointers (k=0); step adds step*32 elems.
  int r0a = (w * 2 + 0) * 16;
  int r0b = (w * 2 + 1) * 16;
  const short* gA0 = xb + (size_t)(m0 + r0a + srow) * Dx + scol;
  const short* gA1 = xb + (size_t)(m0 + r0b + srow) * Dx + scol;
  const short* gB0 = Wm + (size_t)(n0 + r0a + srow) * Dx + scol;
  const short* gB1 = Wm + (size_t)(n0 + r0b + srow) * Dx + scol;

  f32x4 acc[4][4] = {};

#define QSTAGE(step, bf) do {                                             \
    size_t ko = (size_t)(step) * 32;                                      \
    GLDS16(gA0 + ko, &smem[(bf) * 8192 + r0a * 32]);                      \
    GLDS16(gB0 + ko, &smem[(bf) * 8192 + 4096 + r0a * 32]);               \
    GLDS16(gA1 + ko, &smem[(bf) * 8192 + r0b * 32]);                      \
    GLDS16(gB1 + ko, &smem[(bf) * 8192 + 4096 + r0b * 32]);               \
  } while (0)

#define QBODY(step, cur) do {                                             \
    if ((step) < 31) {                                                    \
      QSTAGE((step) + 1, (cur) ^ 1);                                      \
      asm volatile("s_waitcnt vmcnt(4)" ::: "memory");                    \
    } else {                                                              \
      asm volatile("s_waitcnt vmcnt(0)" ::: "memory");                    \
    }                                                                     \
    __builtin_amdgcn_s_barrier();                                         \
    const short* Al = &smem[(cur) * 8192];                                \
    const short* Bl = &smem[(cur) * 8192 + 4096];                         \
    bf16x8 af[4], bfm[4];                                                 \
    _Pragma("unroll")                                                     \
    for (int i = 0; i < 4; ++i)                                           \
      af[i] = *(const bf16x8*)&Al[(wm * 64 + i * 16 + fr) * 32 + cA];     \
    _Pragma("unroll")                                                     \
    for (int i = 0; i < 4; ++i)                                           \
      bfm[i] = *(const bf16x8*)&Bl[(wn * 64 + i * 16 + fr) * 32 + cA];    \
    _Pragma("unroll")                                                     \
    for (int mi = 0; mi < 4; ++mi)                                        \
      _Pragma("unroll")                                                   \
      for (int ni = 0; ni < 4; ++ni)                                      \
        acc[mi][ni] = __builtin_amdgcn_mfma_f32_16x16x32_bf16(            \
            af[mi], bfm[ni], acc[mi][ni], 0, 0, 0);                       \
    __builtin_amdgcn_s_barrier();                                         \
  } while (0)

  QSTAGE(0, 0);

  for (int ks = 0; ks < 32; ks += 2) {
    QBODY(ks, 0);
    QBODY(ks + 1, 1);
  }
#undef QBODY
#undef QSTAGE

  if (which == 2) {
    // ---- V epilogue: bias, transpose via LDS, coalesced swizzled store ----
    __syncthreads();
#pragma unroll
    for (int ni = 0; ni < 4; ++ni) {
      int n_l = wn * 64 + ni * 16 + fr;
      float bias_n = bias[n0 + n_l];
#pragma unroll
      for (int mi = 0; mi < 4; ++mi)
#pragma unroll
        for (int r = 0; r < 4; ++r) {
          int m_l = wm * 64 + mi * 16 + fg * 4 + r;
          smem[n_l * 136 + m_l] = (short)f2bf_u(acc[mi][ni][r] + bias_n);
        }
    }
    __syncthreads();
    int b = m0 >> 11, s0_ = m0 & 2047;   // s0_ multiple of 128
#pragma unroll
    for (int it = 0; it < 8; ++it) {
      int idx2 = t + it * 256;          // 0..2047
      int n_l = idx2 >> 4, c = idx2 & 15;
      int4 v = *(const int4*)&smem[n_l * 136 + c * 8];
      int n = n0 + n_l, h = n >> 6, dh = n & 63;
      int chunk = (c & 7) ^ (dh & 7);
      size_t off = (size_t)(b * Hx + h) * Sx * 64
                 + (size_t)((s0_ >> 6) + (c >> 3)) * 4096
                 + dh * 64 + chunk * 8;
      *(int4*)&vb[off] = v;
    }
    return;
  }

#pragma unroll
  for (int ni = 0; ni < 4; ++ni) {
    int n = n0 + wn * 64 + ni * 16 + fr;
    int h = n >> 6, dh = n & 63;
    float bias_n = bias[n];
#pragma unroll
    for (int mi = 0; mi < 4; ++mi) {
#pragma unroll
      for (int r = 0; r < 4; ++r) {
        int m = m0 + wm * 64 + mi * 16 + fg * 4 + r;
        int b = m >> 11, s = m & 2047;
        float y = acc[mi][ni][r] + bias_n;
        size_t hb = (size_t)(b * Hx + h) * Sx * DHx;
        if (which == 0) {
          qb[hb + (size_t)s * DHx + dh] = (short)f2bf_u(y * C1);
        } else {
          kb[hb + (size_t)s * 64 + ((((dh >> 3) ^ (s & 7)) << 3) | (dh & 7))] =
              (short)f2bf_u(y);
        }
      }
    }
  }
}

// ---------------- Flash attention, swapped-QK 32x32, fixed-scale softmax ----
// grid: (bh=64, qt=8). block: 256 = 4 waves; wave owns 64 query rows as TWO
// 32-row groups (A/B) sharing every K/V LDS fragment read - halves LDS-pipe
// read traffic per q-row. KV tile = 64, double-buffered staging with counted
// vmcnt(4). __launch_bounds__(256,2). The ctx write applies the chunk-XOR
// P(row) so cb matches the GEMM pre-swizzled A-operand layout.
__global__ __launch_bounds__(256, 2) void attn_kernel(
    const short* __restrict__ qb, const short* __restrict__ kb,
    const short* __restrict__ vb, const float* __restrict__ madd,
    const unsigned* __restrict__ maskbits, short* __restrict__ cbuf) {
  int bh = blockIdx.x;   // 0..63 -> XCD = bh&7
  int qt = blockIdx.y;   // 0..7
  int b  = bh >> 4;

  __shared__ alignas(16) short Kl[2][4096];   // [64 s][64 dh] swizzled
  __shared__ alignas(16) short Vt[2][4096];   // [64 dh][64 s] swizzled

  int t = threadIdx.x, l = t & 63, w = t >> 6;
  int lo = l & 31, hi = l >> 5;

  // Q fragments (B-operand) for both q-groups: lane holds Q[q0+lo][...]
  const short* qgA = qb + ((size_t)bh * Sx + qt * 256 + w * 64 + lo) * 64;
  const short* qgB = qgA + 32 * 64;
  bf16x8 qfA[4], qfB[4];
#pragma unroll
  for (int ks = 0; ks < 4; ++ks) {
    qfA[ks] = *(const bf16x8*)&qgA[ks * 16 + hi * 8];
    qfB[ks] = *(const bf16x8*)&qgB[ks * 16 + hi * 8];
  }

  // Loop-invariant per-lane LDS fragment offsets (shorts). Same formula
  // serves K (QK phase) and V (PV phase).
  int koff[4], koff32[4];
#pragma unroll
  for (int ks = 0; ks < 4; ++ks) {
    int c = ((2 * ks + hi) ^ (lo & 7)) << 3;
    koff[ks]   = lo * 64 + c;
    koff32[ks] = (32 + lo) * 64 + c;
  }

  const short* kg = kb + (size_t)bh * Sx * 64;
  const short* vg = vb + (size_t)bh * Sx * 64;
  const float* mg = madd + b * Sx;
  unsigned mbits = maskbits[b];

  bf16x8 ones;
#pragma unroll
  for (int i = 0; i < 8; ++i) ones[i] = (short)0x3F80;

  f32x16 OA0 = {}, OA1 = {}, SsA = {};
  f32x16 OB0 = {}, OB1 = {}, SsB = {};

#define STAGE(tile, bf) do {                                              \
    const short* ks_ = kg + (size_t)(tile) * 4096;                        \
    const short* vs_ = vg + (size_t)(tile) * 4096;                        \
    GLDS16(ks_ + w * 512 + l * 8,        &Kl[bf][w * 512]);               \
    GLDS16(ks_ + 2048 + w * 512 + l * 8, &Kl[bf][2048 + w * 512]);        \
    GLDS16(vs_ + w * 512 + l * 8,        &Vt[bf][w * 512]);               \
    GLDS16(vs_ + 2048 + w * 512 + l * 8, &Vt[bf][2048 + w * 512]);        \
  } while (0)

#define TBODY(tile, cur) do {                                             \
    if ((tile) < 31) {                                                    \
      STAGE((tile) + 1, (cur) ^ 1);                                      \
      asm volatile("s_waitcnt vmcnt(4)" ::: "memory");                    \
    } else {                                                              \
      asm volatile("s_waitcnt vmcnt(0)" ::: "memory");                    \
    }                                                                     \
    __builtin_amdgcn_s_barrier();                                         \
    const short* Kb = &Kl[cur][0];                                        \
    const short* Vb = &Vt[cur][0];                                        \
    f32x16 sA0 = {}, sA1 = {}, sB0 = {}, sB1 = {};                        \
    __builtin_amdgcn_s_setprio(1);                                        \
    _Pragma("unroll")                                                     \
    for (int ks = 0; ks < 4; ++ks) {                                      \
      bf16x8 kf = *(const bf16x8*)&Kb[koff[ks]];                          \
      sA0 = __builtin_amdgcn_mfma_f32_32x32x16_bf16(kf, qfA[ks], sA0, 0, 0, 0); \
      sB0 = __builtin_amdgcn_mfma_f32_32x32x16_bf16(kf, qfB[ks], sB0, 0, 0, 0); \
    }                                                                     \
    _Pragma("unroll")                                                     \
    for (int ks = 0; ks < 4; ++ks) {                                      \
      bf16x8 kf = *(const bf16x8*)&Kb[koff32[ks]];                        \
      sA1 = __builtin_amdgcn_mfma_f32_32x32x16_bf16(kf, qfA[ks], sA1, 0, 0, 0); \
      sB1 = __builtin_amdgcn_mfma_f32_32x32x16_bf16(kf, qfB[ks], sB1, 0, 0, 0); \
    }                                                                     \
    __builtin_amdgcn_s_setprio(0);                                        \
    if ((mbits >> (tile)) & 1) {                                          \
      const float* mrow = mg + (tile) * 64;                               \
      _Pragma("unroll")                                                   \
      for (int r = 0; r < 16; ++r) {                                      \
        int key = (r & 3) + 8 * (r >> 2) + 4 * hi;                        \
        float m0_ = mrow[key], m1_ = mrow[32 + key];                      \
        sA0[r] += m0_; sA1[r] += m1_;                                     \
        sB0[r] += m0_; sB1[r] += m1_;                                     \
      }                                                                   \
    }                                                                     \
    _Pragma("unroll")                                                     \
    for (int r = 0; r < 16; ++r) {                                        \
      sA0[r] = __builtin_amdgcn_exp2f(sA0[r]);                            \
      sA1[r] = __builtin_amdgcn_exp2f(sA1[r]);                            \
      sB0[r] = __builtin_amdgcn_exp2f(sB0[r]);                            \
      sB1[r] = __builtin_amdgcn_exp2f(sB1[r]);                            \
    }                                                                     \
    __builtin_amdgcn_s_setprio(1);                                        \
    _Pragma("unroll")                                                     \
    for (int kbi = 0; kbi < 2; ++kbi) {                                   \
      _Pragma("unroll")                                                   \
      for (int half = 0; half < 2; ++half) {                              \
        int po = half * 8;                                                \
        unsigned int uA, uA2, vA, vA2, uB, uB2, vB, vB2;                  \
        if (kbi == 0) {                                                   \
          uA  = cvtpk(sA0[po + 0], sA0[po + 1]);                          \
          uA2 = cvtpk(sA0[po + 2], sA0[po + 3]);                          \
          vA  = cvtpk(sA0[po + 4], sA0[po + 5]);                          \
          vA2 = cvtpk(sA0[po + 6], sA0[po + 7]);                          \
          uB  = cvtpk(sB0[po + 0], sB0[po + 1]);                          \
          uB2 = cvtpk(sB0[po + 2], sB0[po + 3]);                          \
          vB  = cvtpk(sB0[po + 4], sB0[po + 5]);                          \
          vB2 = cvtpk(sB0[po + 6], sB0[po + 7]);                          \
        } else {                                                          \
          uA  = cvtpk(sA1[po + 0], sA1[po + 1]);                          \
          uA2 = cvtpk(sA1[po + 2], sA1[po + 3]);                          \
          vA  = cvtpk(sA1[po + 4], sA1[po + 5]);                          \
          vA2 = cvtpk(sA1[po + 6], sA1[po + 7]);                          \
          uB  = cvtpk(sB1[po + 0], sB1[po + 1]);                          \
          uB2 = cvtpk(sB1[po + 2], sB1[po + 3]);                          \
          vB  = cvtpk(sB1[po + 4], sB1[po + 5]);                          \
          vB2 = cvtpk(sB1[po + 6], sB1[po + 7]);                          \
        }                                                                 \
        swap32(vA, uA); swap32(vA2, uA2);                                 \
        swap32(vB, uB); swap32(vB2, uB2);                                 \
        union { unsigned int i[4]; bf16x8 v8; } puA, puB;                 \
        puA.i[0] = uA; puA.i[1] = uA2; puA.i[2] = vA; puA.i[3] = vA2;     \
        puB.i[0] = uB; puB.i[1] = uB2; puB.i[2] = vB; puB.i[3] = vB2;     \
        int vi = kbi * 2 + half;                                          \
        bf16x8 vf0 = *(const bf16x8*)&Vb[koff[vi]];                       \
        bf16x8 vf1 = *(const bf16x8*)&Vb[koff32[vi]];                     \
        OA0 = __builtin_amdgcn_mfma_f32_32x32x16_bf16(puA.v8, vf0, OA0, 0, 0, 0); \
        OA1 = __builtin_amdgcn_mfma_f32_32x32x16_bf16(puA.v8, vf1, OA1, 0, 0, 0); \
        SsA = __builtin_amdgcn_mfma_f32_32x32x16_bf16(puA.v8, ones, SsA, 0, 0, 0); \
        OB0 = __builtin_amdgcn_mfma_f32_32x32x16_bf16(puB.v8, vf0, OB0, 0, 0, 0); \
        OB1 = __builtin_amdgcn_mfma_f32_32x32x16_bf16(puB.v8, vf1, OB1, 0, 0, 0); \
        SsB = __builtin_amdgcn_mfma_f32_32x32x16_bf16(puB.v8, ones, SsB, 0, 0, 0); \
      }                                                                   \
    }                                                                     \
    __builtin_amdgcn_s_setprio(0);                                        \
    __builtin_amdgcn_s_barrier();                                        \
  } while (0)

  STAGE(0, 0);

  for (int tile = 0; tile < 32; tile += 2) {
    TBODY(tile, 0);
    TBODY(tile + 1, 1);
  }
#undef TBODY
#undef STAGE

  // ---- normalize + write ctx (chunk-swizzled cb for proj's A-operand) ----
  int h = bh & 15, bq_ = bh >> 4;
  int loLo = lo & 7, loCh = lo >> 3;   // chunk/offset of this lane's column
#pragma unroll
  for (int a = 0; a < 4; ++a) {
#pragma unroll
    for (int j = 0; j < 4; ++j) {
      int r = a * 4 + j;
      int srow = a * 8 + hi * 4 + j;
      int p = (srow & 3) ^ ((srow >> 2) & 3);   // P(row); rows sA,sB share it
      int colp = ((loCh ^ p) << 3) | loLo;      // permuted within 32-col block
      float linvA = __builtin_amdgcn_rcpf(SsA[r]);
      float linvB = __builtin_amdgcn_rcpf(SsB[r]);
      int sA = qt * 256 + w * 64 + srow;
      int sB = sA + 32;
      size_t rowbA = ((size_t)(bq_ * Sx + sA)) * Dx + h * 64;
      size_t rowbB = ((size_t)(bq_ * Sx + sB)) * Dx + h * 64;
      cbuf[rowbA + colp]      = (short)f2bf_u(OA0[r] * linvA);
      cbuf[rowbA + 32 + colp] = (short)f2bf_u(OA1[r] * linvA);
      cbuf[rowbB + colp]      = (short)f2bf_u(OB0[r] * linvB);
      cbuf[rowbB + 32 + colp] = (short)f2bf_u(OB1[r] * linvB);
    }
  }
}

// ---------------- Output proj GEMM + bias + residual (fp32 out) -----------
// 128x128 tile, BK=32, 2-PHASE double-buffered staging (compile-time buffer
// index, hoisted bases, vmcnt(4), no setprio - the R18-proven qkv pattern);
// XCD-aware swizzle; chunk-XOR fragment reads match pre-swizzled cb/wb.
__global__ __launch_bounds__(256) void proj_gemm(
    const short* __restrict__ cb, const short* __restrict__ wo,
    const float* __restrict__ bo, const float* __restrict__ x,
    float* __restrict__ out) {
  int lid = blockIdx.x + (blockIdx.y << 3);   // grid = dim3(8,64)
  int xcd = lid & 7;
  int tt = lid >> 3;           // 0..63
  int m0 = (xcd * 8 + (tt >> 3)) * 128;
  int n0 = (tt & 7) * 128;

  __shared__ alignas(16) short smem[2 * 8192];

  int t = threadIdx.x;
  int l = t & 63, w = t >> 6;
  int wm = w >> 1, wn = w & 1;
  int srow = l >> 2, scol = (l & 3) * 8;
  int fr = l & 15, fg = l >> 4;
  int pl = (fr & 3) ^ ((fr >> 2) & 3);
  int cA = ((fg ^ pl) << 3);

  int r0a = (w * 2 + 0) * 16;
  int r0b = (w * 2 + 1) * 16;
  const short* gA0 = cb + (size_t)(m0 + r0a + srow) * Dx + scol;
  const short* gA1 = cb + (size_t)(m0 + r0b + srow) * Dx + scol;
  const short* gB0 = wo + (size_t)(n0 + r0a + srow) * Dx + scol;
  const short* gB1 = wo + (size_t)(n0 + r0b + srow) * Dx + scol;

  f32x4 acc[4][4] = {};

#define PSTAGE(step, bf) do {                                             \
    size_t ko = (size_t)(step) * 32;                                      \
    GLDS16(gA0 + ko, &smem[(bf) * 8192 + r0a * 32]);                      \
    GLDS16(gB0 + ko, &smem[(bf) * 8192 + 4096 + r0a * 32]);               \
    GLDS16(gA1 + ko, &smem[(bf) * 8192 + r0b * 32]);                      \
    GLDS16(gB1 + ko, &smem[(bf) * 8192 + 4096 + r0b * 32]);               \
  } while (0)

#define PBODY(step, cur) do {                                             \
    if ((step) < 31) {                                                    \
      PSTAGE((step) + 1, (cur) ^ 1);                                      \
      asm volatile("s_waitcnt vmcnt(4)" ::: "memory");                    \
    } else {                                                              \
      asm volatile("s_waitcnt vmcnt(0)" ::: "memory");                    \
    }                                                                     \
    __builtin_amdgcn_s_barrier();                                         \
    const short* Al = &smem[(cur) * 8192];                                \
    const short* Bl = &smem[(cur) * 8192 + 4096];                         \
    bf16x8 af[4], bfm[4];                                                 \
    _Pragma("unroll")                                                     \
    for (int i = 0; i < 4; ++i)                                           \
      af[i] = *(const bf16x8*)&Al[(wm * 64 + i * 16 + fr) * 32 + cA];     \
    _Pragma("unroll")                                                     \
    for (int i = 0; i < 4; ++i)                                           \
      bfm[i] = *(const bf16x8*)&Bl[(wn * 64 + i * 16 + fr) * 32 + cA];    \
    _Pragma("unroll")                                                     \
    for (int mi = 0; mi < 4; ++mi)                                        \
      _Pragma("unroll")                                                   \
      for (int ni = 0; ni < 4; ++ni)                                      \
        acc[mi][ni] = __builtin_amdgcn_mfma_f32_16x16x32_bf16(            \
            af[mi], bfm[ni], acc[mi][ni], 0, 0, 0);                       \
    __builtin_amdgcn_s_barrier();                                         \
  } while (0)

  PSTAGE(0, 0);

  for (int ks = 0; ks < 32; ks += 2) {
    PBODY(ks, 0);
    PBODY(ks + 1, 1);
  }
#undef PBODY
#undef PSTAGE

#pragma unroll
  for (int ni = 0; ni < 4; ++ni) {
    int n = n0 + wn * 64 + ni * 16 + fr;
    float bias_n = bo[n];
#pragma unroll
    for (int mi = 0; mi < 4; ++mi) {
#pragma unroll
      for (int r = 0; r < 4; ++r) {
        int m = m0 + wm * 64 + mi * 16 + fg * 4 + r;
        float y = acc[mi][ni][r] + bias_n + x[(size_t)m * Dx + n];
        out[(size_t)m * Dx + n] = y;
      }
    }
  }
}

// ---------------- LayerNorm (in-place on fp32 rows of 1024) ---------------
__global__ __launch_bounds__(256) void ln_kernel(float* __restrict__ io,
                                                 const float* __restrict__ lw,
                                                 const float* __restrict__ lb) {
  int row = blockIdx.x;
  float* p = io + (size_t)row * Dx;
  int c = threadIdx.x * 4;
  float4 v = *(float4*)&p[c];
  float s = v.x + v.y + v.z + v.w;
  float q = v.x * v.x + v.y * v.y + v.z * v.z + v.w * v.w;
#pragma unroll
  for (int d = 1; d < 64; d <<= 1) {
    s += __shfl_xor(s, d, 64);
    q += __shfl_xor(q, d, 64);
  }
  __shared__ float ss[4], qq[4];
  int l = threadIdx.x & 63, w = threadIdx.x >> 6;
  if (l == 0) { ss[w] = s; qq[w] = q; }
  __syncthreads();
  s = ss[0] + ss[1] + ss[2] + ss[3];
  q = qq[0] + qq[1] + qq[2] + qq[3];
  float mu = s * (1.f / Dx);
  float var = q * (1.f / Dx) - mu * mu;
  float rstd = rsqrtf(var + 1e-5f);
  float4 w4 = *(const float4*)&lw[c];
  float4 b4 = *(const float4*)&lb[c];
  float4 o;
  o.x = (v.x - mu) * rstd * w4.x + b4.x;
  o.y = (v.y - mu) * rstd * w4.y + b4.y;
  o.z = (v.z - mu) * rstd * w4.z + b4.z;
  o.w = (v.w - mu) * rstd * w4.w + b4.w;
  *(float4*)&p[c] = o;
}

// ---------------- launch ----------------
extern "C" void kernel_launch(void* const* d_in, const int* in_sizes, int n_in,
                              void* d_out, int out_size, void* d_ws, size_t ws_size,
                              hipStream_t stream) {
  const float* x   = (const float*)d_in[0];
  const int*   msk = (const int*)d_in[1];
  const float* Wq  = (const float*)d_in[2];
  const float* bq  = (const float*)d_in[3];
  const float* Wk  = (const float*)d_in[4];
  const float* bk  = (const float*)d_in[5];
  const float* Wv  = (const float*)d_in[6];
  const float* bv  = (const float*)d_in[7];
  const float* Wo  = (const float*)d_in[8];
  const float* bo  = (const float*)d_in[9];
  const float* lnw = (const float*)d_in[10];
  const float* lnb = (const float*)d_in[11];
  float* out = (float*)d_out;

  // Workspace layout (88 MB total)
  char* ws = (char*)d_ws;
  short* xb = (short*)(ws);                          // 16 MB  bf16 x (chunk-swz)
  short* wb = (short*)(ws + (size_t)(16 << 20));     //  8 MB  bf16 W (chunk-swz)
  short* qb = (short*)(ws + (size_t)(24 << 20));     // 16 MB  bf16 Q (pre-scaled)
  short* kb = (short*)(ws + (size_t)(40 << 20));     // 16 MB  bf16 K swizzled
  short* vb = (short*)(ws + (size_t)(56 << 20));     // 16 MB  bf16 V^T swizzled
  short* cb = (short*)(ws + (size_t)(72 << 20));     // 16 MB  bf16 ctx (chunk-swz)
  float* madd = out;                        // d_out scratch, overwritten by proj
  unsigned* mbits = (unsigned*)(out + Mx);  // 4 uints after madd

  prep_kernel<<<6180, 256, 0, stream>>>(x, Wq, Wk, Wv, Wo, msk,
                                        (uint4*)xb, (uint4*)wb, madd, mbits);
  qkv_gemm<<<dim3(8, 64, 3), 256, 0, stream>>>(xb, wb, bq, bk, bv, qb, kb, vb);
  attn_kernel<<<dim3(64, 8), 256, 0, stream>>>(qb, kb, vb, madd, mbits, cb);
  proj_gemm<<<dim3(8, 64), 256, 0, stream>>>(cb, wb + 3 * (size_t)(Dx * Dx), bo, x, out);
  ln_kernel<<<Mx, 256, 0, stream>>>(out, lnw, lnb);
}

// Round 20
// 195.347 us; speedup vs baseline: 1.0912x; 1.0326x over previous
//
#include <hip/hip_runtime.h>
#include <hip/hip_bf16.h>
#include <stdint.h>

// Problem constants
#define Bx  4
#define Sx  2048
#define Dx  1024
#define Hx  16
#define DHx 64
#define Mx  (Bx*Sx)   // 8192

typedef short bf16x8 __attribute__((ext_vector_type(8)));
typedef float f32x4  __attribute__((ext_vector_type(4)));
typedef float f32x16 __attribute__((ext_vector_type(16)));

#define C1 0.18033688f   // 0.125 * log2(e)

__device__ __forceinline__ unsigned short f2bf_u(float f) {
  union { float f; unsigned int u; } c; c.f = f;
  return (unsigned short)((c.u + 0x7fffu + ((c.u >> 16) & 1u)) >> 16);
}
__device__ __forceinline__ unsigned int pack2(float lo, float hi) {
  return ((unsigned int)f2bf_u(hi) << 16) | (unsigned int)f2bf_u(lo);
}
// packed f32->bf16 (RNE), lo -> bits[15:0], hi -> bits[31:16]
__device__ __forceinline__ unsigned int cvtpk(float lo_, float hi_) {
  unsigned int r;
  asm("v_cvt_pk_bf16_f32 %0, %1, %2" : "=v"(r) : "v"(lo_), "v"(hi_));
  return r;
}
// swap low 32 lanes of d with high 32 lanes of s
__device__ __forceinline__ void swap32(unsigned int& d, unsigned int& s) {
  asm("v_permlane32_swap_b32 %0, %1" : "+v"(d), "+v"(s));
}

#define GLDS16(gp, lp) __builtin_amdgcn_global_load_lds( \
  (const __attribute__((address_space(1))) unsigned int*)(gp), \
  (__attribute__((address_space(3))) unsigned int*)(lp), 16, 0, 0)

// ---------------- fused prep: cvt x + 4 weights, madd, maskbits ----------
// grid layout: [0,4096) x-cvt | [4096,6144) W-cvt (512 blocks each) |
//              [6144,6176) madd | [6176,6180) maskbits
// xb/wb stored CHUNK-SWIZZLED: c ^= P(row), P(row)=(row&3)^((row>>2)&3).
__global__ __launch_bounds__(256) void prep_kernel(
    const float* __restrict__ x,  const float* __restrict__ Wq,
    const float* __restrict__ Wk, const float* __restrict__ Wv,
    const float* __restrict__ Wo, const int* __restrict__ mask,
    uint4* __restrict__ xb4, uint4* __restrict__ wb4,
    float* __restrict__ madd, unsigned* __restrict__ mb) {
  int bid = blockIdx.x, t = threadIdx.x;
  if (bid < 6144) {
    const float* src;
    uint4* dst;
    int i;
    if (bid < 4096) {
      src = x; dst = xb4; i = bid * 256 + t;
    } else {
      int wbid = bid - 4096;          // 0..2047
      int widx = wbid >> 9;           // 0..3
      src = (widx == 0) ? Wq : (widx == 1) ? Wk : (widx == 2) ? Wv : Wo;
      dst = wb4 + (size_t)widx * 131072;
      i = (wbid & 511) * 256 + t;
    }
    const float4* s = (const float4*)src + (size_t)i * 2;
    float4 a = s[0], b = s[1];
    uint4 o;
    o.x = pack2(a.x, a.y); o.y = pack2(a.z, a.w);
    o.z = pack2(b.x, b.y); o.w = pack2(b.z, b.w);
    int ip = (i & ~3) | ((i & 3) ^ ((i >> 7) & 3) ^ ((i >> 9) & 3));
    dst[ip] = o;
  } else if (bid < 6176) {
    int i = (bid - 6144) * 256 + t;   // 0..8191
    madd[i] = (mask[i] == 0) ? -1e30f : 0.0f;
  } else {
    int b = bid - 6176;               // 0..3
    if (t < 64) {
      int any = 0;
      if (t < 32) {
        for (int i = 0; i < 64; ++i) any |= (mask[b * Sx + t * 64 + i] == 0);
      }
      unsigned long long bits = __ballot(any != 0);
      if (t == 0) mb[b] = (unsigned)bits;
    }
  }
}

// ---------------- QKV GEMM: y = x @ W^T + b ----
// 128x128 tile, BK=32, 4 waves. 3-BUFFER DEPTH-2 pipelined global_load_lds
// staging: two stages in flight over each compute phase (vmcnt(8) waits only
// for the current buffer's 4 loads) -> hides ~2x compute ~ full L3 latency.
// Compile-time buffer indices via 3-periodic unroll (R15 lesson: runtime bf
// costs 40pt VALUBusy); hoisted per-lane base pointers; NO setprio. Depth-1
// version (R18) measured 79us; serial 83us.
// XCD-aware swizzle: xcd = lid&7 owns m_tiles [xcd*8, xcd*8+8) x all n, per z.
// Fragment reads XOR chunk with pl=(fr&3)^((fr>>2)&3) (prep layout).
// Output layouts (per head, head base = (b*16+h)*S*64):
//  Q: normal [B,H,S,DH], PRE-SCALED by C1 (log2-domain scores)
//  K: tile-linear swizzled: elem (s,dh) at s*64 + (((dh>>3)^(s&7))<<3) + (dh&7)
//  V: transposed tile-linear swizzled (tiles of 64 s):
//     elem (s,dh) at (s>>6)*4096 + dh*64 + ((((s>>3)&7)^(dh&7))<<3) + (s&7)
__global__ __launch_bounds__(256) void qkv_gemm(
    const short* __restrict__ xb, const short* __restrict__ wb,
    const float* __restrict__ bq, const float* __restrict__ bk,
    const float* __restrict__ bv,
    short* __restrict__ qb, short* __restrict__ kb, short* __restrict__ vb) {
  // linear wg id (grid = dim3(8,64,3)); xcd = lid&7 by dispatch round-robin
  int lid = blockIdx.x + (blockIdx.y << 3) + (blockIdx.z << 9);
  int xcd = lid & 7;
  int idx = lid >> 3;          // 0..191
  int which = idx >> 6;        // 0..2
  int tt = idx & 63;           // 0..63
  int m0 = (xcd * 8 + (tt >> 3)) * 128;
  int n0 = (tt & 7) * 128;

  const short* Wm  = wb + (size_t)which * Dx * Dx;
  const float* bias = (which == 0) ? bq : (which == 1 ? bk : bv);

  // 3 staging buffers (3 x 8192 shorts = 48 KB); V epilogue reuses the
  // first 128*136 = 17408 shorts as a transpose buffer.
  __shared__ alignas(16) short smem[3 * 8192];

  int t = threadIdx.x;
  int l = t & 63, w = t >> 6;
  int wm = w >> 1, wn = w & 1;
  int srow = l >> 2;
  int scol = (l & 3) * 8;
  int fr = l & 15, fg = l >> 4;
  int pl = (fr & 3) ^ ((fr >> 2) & 3);     // chunk-XOR (matches prep layout)
  int cA = ((fg ^ pl) << 3);               // per-lane constant read chunk

  // Hoisted per-lane staging base pointers (k=0); step adds step*32 elems.
  int r0a = (w * 2 + 0) * 16;
  int r0b = (w * 2 + 1) * 16;
  const short* gA0 = xb + (size_t)(m0 + r0a + srow) * Dx + scol;
  const short* gA1 = xb + (size_t)(m0 + r0b + srow) * Dx + scol;
  const short* gB0 = Wm + (size_t)(n0 + r0a + srow) * Dx + scol;
  const short* gB1 = Wm + (size_t)(n0 + r0b + srow) * Dx + scol;

  f32x4 acc[4][4] = {};

#define QSTAGE(step, bf) do {                                             \
    size_t ko = (size_t)(step) * 32;                                      \
    GLDS16(gA0 + ko, &smem[(bf) * 8192 + r0a * 32]);                      \
    GLDS16(gB0 + ko, &smem[(bf) * 8192 + 4096 + r0a * 32]);               \
    GLDS16(gA1 + ko, &smem[(bf) * 8192 + r0b * 32]);                      \
    GLDS16(gB1 + ko, &smem[(bf) * 8192 + 4096 + r0b * 32]);               \
  } while (0)

// depth-2: at compute(step), stages step+1 and step+2 are in flight.
#define QBODY(step, cur, nbf) do {                                        \
    if ((step) < 30) {                                                    \
      QSTAGE((step) + 2, (nbf));                                          \
      asm volatile("s_waitcnt vmcnt(8)" ::: "memory");                    \
    } else if ((step) == 30) {                                            \
      asm volatile("s_waitcnt vmcnt(4)" ::: "memory");                    \
    } else {                                                              \
      asm volatile("s_waitcnt vmcnt(0)" ::: "memory");                    \
    }                                                                     \
    __builtin_amdgcn_s_barrier();                                         \
    const short* Al = &smem[(cur) * 8192];                                \
    const short* Bl = &smem[(cur) * 8192 + 4096];                         \
    bf16x8 af[4], bfm[4];                                                 \
    _Pragma("unroll")                                                     \
    for (int i = 0; i < 4; ++i)                                           \
      af[i] = *(const bf16x8*)&Al[(wm * 64 + i * 16 + fr) * 32 + cA];     \
    _Pragma("unroll")                                                     \
    for (int i = 0; i < 4; ++i)                                           \
      bfm[i] = *(const bf16x8*)&Bl[(wn * 64 + i * 16 + fr) * 32 + cA];    \
    _Pragma("unroll")                                                     \
    for (int mi = 0; mi < 4; ++mi)                                        \
      _Pragma("unroll")                                                   \
      for (int ni = 0; ni < 4; ++ni)                                      \
        acc[mi][ni] = __builtin_amdgcn_mfma_f32_16x16x32_bf16(            \
            af[mi], bfm[ni], acc[mi][ni], 0, 0, 0);                       \
    __builtin_amdgcn_s_barrier();                                         \
  } while (0)

  QSTAGE(0, 0);
  QSTAGE(1, 1);

  for (int ks = 0; ks < 30; ks += 3) {
    QBODY(ks,     0, 2);
    QBODY(ks + 1, 1, 0);
    QBODY(ks + 2, 2, 1);
  }
  QBODY(30, 0, 0);   // 30 % 3 == 0
  QBODY(31, 1, 0);   // 31 % 3 == 1
#undef QBODY
#undef QSTAGE

  if (which == 2) {
    // ---- V epilogue: bias, transpose via LDS, coalesced swizzled store ----
    __syncthreads();
#pragma unroll
    for (int ni = 0; ni < 4; ++ni) {
      int n_l = wn * 64 + ni * 16 + fr;
      float bias_n = bias[n0 + n_l];
#pragma unroll
      for (int mi = 0; mi < 4; ++mi)
#pragma unroll
        for (int r = 0; r < 4; ++r) {
          int m_l = wm * 64 + mi * 16 + fg * 4 + r;
          smem[n_l * 136 + m_l] = (short)f2bf_u(acc[mi][ni][r] + bias_n);
        }
    }
    __syncthreads();
    int b = m0 >> 11, s0_ = m0 & 2047;   // s0_ multiple of 128
#pragma unroll
    for (int it = 0; it < 8; ++it) {
      int idx2 = t + it * 256;          // 0..2047
      int n_l = idx2 >> 4, c = idx2 & 15;
      int4 v = *(const int4*)&smem[n_l * 136 + c * 8];
      int n = n0 + n_l, h = n >> 6, dh = n & 63;
      int chunk = (c & 7) ^ (dh & 7);
      size_t off = (size_t)(b * Hx + h) * Sx * 64
                 + (size_t)((s0_ >> 6) + (c >> 3)) * 4096
                 + dh * 64 + chunk * 8;
      *(int4*)&vb[off] = v;
    }
    return;
  }

#pragma unroll
  for (int ni = 0; ni < 4; ++ni) {
    int n = n0 + wn * 64 + ni * 16 + fr;
    int h = n >> 6, dh = n & 63;
    float bias_n = bias[n];
#pragma unroll
    for (int mi = 0; mi < 4; ++mi) {
#pragma unroll
      for (int r = 0; r < 4; ++r) {
        int m = m0 + wm * 64 + mi * 16 + fg * 4 + r;
        int b = m >> 11, s = m & 2047;
        float y = acc[mi][ni][r] + bias_n;
        size_t hb = (size_t)(b * Hx + h) * Sx * DHx;
        if (which == 0) {
          qb[hb + (size_t)s * DHx + dh] = (short)f2bf_u(y * C1);
        } else {
          kb[hb + (size_t)s * 64 + ((((dh >> 3) ^ (s & 7)) << 3) | (dh & 7))] =
              (short)f2bf_u(y);
        }
      }
    }
  }
}

// ---------------- Flash attention, swapped-QK 32x32, fixed-scale softmax ----
// grid: (bh=64, qt=8). block: 256 = 4 waves; wave owns 64 query rows as TWO
// 32-row groups (A/B) sharing every K/V LDS fragment read - halves LDS-pipe
// read traffic per q-row. KV tile = 64, double-buffered staging with counted
// vmcnt(4). __launch_bounds__(256,2). The ctx write applies the chunk-XOR
// P(row) so cb matches the GEMM pre-swizzled A-operand layout.
__global__ __launch_bounds__(256, 2) void attn_kernel(
    const short* __restrict__ qb, const short* __restrict__ kb,
    const short* __restrict__ vb, const float* __restrict__ madd,
    const unsigned* __restrict__ maskbits, short* __restrict__ cbuf) {
  int bh = blockIdx.x;   // 0..63 -> XCD = bh&7
  int qt = blockIdx.y;   // 0..7
  int b  = bh >> 4;

  __shared__ alignas(16) short Kl[2][4096];   // [64 s][64 dh] swizzled
  __shared__ alignas(16) short Vt[2][4096];   // [64 dh][64 s] swizzled

  int t = threadIdx.x, l = t & 63, w = t >> 6;
  int lo = l & 31, hi = l >> 5;

  // Q fragments (B-operand) for both q-groups: lane holds Q[q0+lo][...]
  const short* qgA = qb + ((size_t)bh * Sx + qt * 256 + w * 64 + lo) * 64;
  const short* qgB = qgA + 32 * 64;
  bf16x8 qfA[4], qfB[4];
#pragma unroll
  for (int ks = 0; ks < 4; ++ks) {
    qfA[ks] = *(const bf16x8*)&qgA[ks * 16 + hi * 8];
    qfB[ks] = *(const bf16x8*)&qgB[ks * 16 + hi * 8];
  }

  // Loop-invariant per-lane LDS fragment offsets (shorts). Same formula
  // serves K (QK phase) and V (PV phase).
  int koff[4], koff32[4];
#pragma unroll
  for (int ks = 0; ks < 4; ++ks) {
    int c = ((2 * ks + hi) ^ (lo & 7)) << 3;
    koff[ks]   = lo * 64 + c;
    koff32[ks] = (32 + lo) * 64 + c;
  }

  const short* kg = kb + (size_t)bh * Sx * 64;
  const short* vg = vb + (size_t)bh * Sx * 64;
  const float* mg = madd + b * Sx;
  unsigned mbits = maskbits[b];

  bf16x8 ones;
#pragma unroll
  for (int i = 0; i < 8; ++i) ones[i] = (short)0x3F80;

  f32x16 OA0 = {}, OA1 = {}, SsA = {};
  f32x16 OB0 = {}, OB1 = {}, SsB = {};

#define STAGE(tile, bf) do {                                              \
    const short* ks_ = kg + (size_t)(tile) * 4096;                        \
    const short* vs_ = vg + (size_t)(tile) * 4096;                        \
    GLDS16(ks_ + w * 512 + l * 8,        &Kl[bf][w * 512]);               \
    GLDS16(ks_ + 2048 + w * 512 + l * 8, &Kl[bf][2048 + w * 512]);        \
    GLDS16(vs_ + w * 512 + l * 8,        &Vt[bf][w * 512]);               \
    GLDS16(vs_ + 2048 + w * 512 + l * 8, &Vt[bf][2048 + w * 512]);        \
  } while (0)

#define TBODY(tile, cur) do {                                             \
    if ((tile) < 31) {                                                    \
      STAGE((tile) + 1, (cur) ^ 1);                                      \
      asm volatile("s_waitcnt vmcnt(4)" ::: "memory");                    \
    } else {                                                              \
      asm volatile("s_waitcnt vmcnt(0)" ::: "memory");                    \
    }                                                                     \
    __builtin_amdgcn_s_barrier();                                         \
    const short* Kb = &Kl[cur][0];                                        \
    const short* Vb = &Vt[cur][0];                                        \
    f32x16 sA0 = {}, sA1 = {}, sB0 = {}, sB1 = {};                        \
    __builtin_amdgcn_s_setprio(1);                                        \
    _Pragma("unroll")                                                     \
    for (int ks = 0; ks < 4; ++ks) {                                      \
      bf16x8 kf = *(const bf16x8*)&Kb[koff[ks]];                          \
      sA0 = __builtin_amdgcn_mfma_f32_32x32x16_bf16(kf, qfA[ks], sA0, 0, 0, 0); \
      sB0 = __builtin_amdgcn_mfma_f32_32x32x16_bf16(kf, qfB[ks], sB0, 0, 0, 0); \
    }                                                                     \
    _Pragma("unroll")                                                     \
    for (int ks = 0; ks < 4; ++ks) {                                      \
      bf16x8 kf = *(const bf16x8*)&Kb[koff32[ks]];                        \
      sA1 = __builtin_amdgcn_mfma_f32_32x32x16_bf16(kf, qfA[ks], sA1, 0, 0, 0); \
      sB1 = __builtin_amdgcn_mfma_f32_32x32x16_bf16(kf, qfB[ks], sB1, 0, 0, 0); \
    }                                                                     \
    __builtin_amdgcn_s_setprio(0);                                        \
    if ((mbits >> (tile)) & 1) {                                          \
      const float* mrow = mg + (tile) * 64;                               \
      _Pragma("unroll")                                                   \
      for (int r = 0; r < 16; ++r) {                                      \
        int key = (r & 3) + 8 * (r >> 2) + 4 * hi;                        \
        float m0_ = mrow[key], m1_ = mrow[32 + key];                      \
        sA0[r] += m0_; sA1[r] += m1_;                                     \
        sB0[r] += m0_; sB1[r] += m1_;                                     \
      }                                                                   \
    }                                                                     \
    _Pragma("unroll")                                                     \
    for (int r = 0; r < 16; ++r) {                                        \
      sA0[r] = __builtin_amdgcn_exp2f(sA0[r]);                            \
      sA1[r] = __builtin_amdgcn_exp2f(sA1[r]);                            \
      sB0[r] = __builtin_amdgcn_exp2f(sB0[r]);                            \
      sB1[r] = __builtin_amdgcn_exp2f(sB1[r]);                            \
    }                                                                     \
    __builtin_amdgcn_s_setprio(1);                                        \
    _Pragma("unroll")                                                     \
    for (int kbi = 0; kbi < 2; ++kbi) {                                   \
      _Pragma("unroll")                                                   \
      for (int half = 0; half < 2; ++half) {                              \
        int po = half * 8;                                                \
        unsigned int uA, uA2, vA, vA2, uB, uB2, vB, vB2;                  \
        if (kbi == 0) {                                                   \
          uA  = cvtpk(sA0[po + 0], sA0[po + 1]);                          \
          uA2 = cvtpk(sA0[po + 2], sA0[po + 3]);                          \
          vA  = cvtpk(sA0[po + 4], sA0[po + 5]);                          \
          vA2 = cvtpk(sA0[po + 6], sA0[po + 7]);                          \
          uB  = cvtpk(sB0[po + 0], sB0[po + 1]);                          \
          uB2 = cvtpk(sB0[po + 2], sB0[po + 3]);                          \
          vB  = cvtpk(sB0[po + 4], sB0[po + 5]);                          \
          vB2 = cvtpk(sB0[po + 6], sB0[po + 7]);                          \
        } else {                                                          \
          uA  = cvtpk(sA1[po + 0], sA1[po + 1]);                          \
          uA2 = cvtpk(sA1[po + 2], sA1[po + 3]);                          \
          vA  = cvtpk(sA1[po + 4], sA1[po + 5]);                          \
          vA2 = cvtpk(sA1[po + 6], sA1[po + 7]);                          \
          uB  = cvtpk(sB1[po + 0], sB1[po + 1]);                          \
          uB2 = cvtpk(sB1[po + 2], sB1[po + 3]);                          \
          vB  = cvtpk(sB1[po + 4], sB1[po + 5]);                          \
          vB2 = cvtpk(sB1[po + 6], sB1[po + 7]);                          \
        }                                                                 \
        swap32(vA, uA); swap32(vA2, uA2);                                 \
        swap32(vB, uB); swap32(vB2, uB2);                                 \
        union { unsigned int i[4]; bf16x8 v8; } puA, puB;                 \
        puA.i[0] = uA; puA.i[1] = uA2; puA.i[2] = vA; puA.i[3] = vA2;     \
        puB.i[0] = uB; puB.i[1] = uB2; puB.i[2] = vB; puB.i[3] = vB2;     \
        int vi = kbi * 2 + half;                                          \
        bf16x8 vf0 = *(const bf16x8*)&Vb[koff[vi]];                       \
        bf16x8 vf1 = *(const bf16x8*)&Vb[koff32[vi]];                     \
        OA0 = __builtin_amdgcn_mfma_f32_32x32x16_bf16(puA.v8, vf0, OA0, 0, 0, 0); \
        OA1 = __builtin_amdgcn_mfma_f32_32x32x16_bf16(puA.v8, vf1, OA1, 0, 0, 0); \
        SsA = __builtin_amdgcn_mfma_f32_32x32x16_bf16(puA.v8, ones, SsA, 0, 0, 0); \
        OB0 = __builtin_amdgcn_mfma_f32_32x32x16_bf16(puB.v8, vf0, OB0, 0, 0, 0); \
        OB1 = __builtin_amdgcn_mfma_f32_32x32x16_bf16(puB.v8, vf1, OB1, 0, 0, 0); \
        SsB = __builtin_amdgcn_mfma_f32_32x32x16_bf16(puB.v8, ones, SsB, 0, 0, 0); \
      }                                                                   \
    }                                                                     \
    __builtin_amdgcn_s_setprio(0);                                        \
    __builtin_amdgcn_s_barrier();                                        \
  } while (0)

  STAGE(0, 0);

  for (int tile = 0; tile < 32; tile += 2) {
    TBODY(tile, 0);
    TBODY(tile + 1, 1);
  }
#undef TBODY
#undef STAGE

  // ---- normalize + write ctx (chunk-swizzled cb for proj's A-operand) ----
  int h = bh & 15, bq_ = bh >> 4;
  int loLo = lo & 7, loCh = lo >> 3;   // chunk/offset of this lane's column
#pragma unroll
  for (int a = 0; a < 4; ++a) {
#pragma unroll
    for (int j = 0; j < 4; ++j) {
      int r = a * 4 + j;
      int srow = a * 8 + hi * 4 + j;
      int p = (srow & 3) ^ ((srow >> 2) & 3);   // P(row); rows sA,sB share it
      int colp = ((loCh ^ p) << 3) | loLo;      // permuted within 32-col block
      float linvA = __builtin_amdgcn_rcpf(SsA[r]);
      float linvB = __builtin_amdgcn_rcpf(SsB[r]);
      int sA = qt * 256 + w * 64 + srow;
      int sB = sA + 32;
      size_t rowbA = ((size_t)(bq_ * Sx + sA)) * Dx + h * 64;
      size_t rowbB = ((size_t)(bq_ * Sx + sB)) * Dx + h * 64;
      cbuf[rowbA + colp]      = (short)f2bf_u(OA0[r] * linvA);
      cbuf[rowbA + 32 + colp] = (short)f2bf_u(OA1[r] * linvA);
      cbuf[rowbB + colp]      = (short)f2bf_u(OB0[r] * linvB);
      cbuf[rowbB + 32 + colp] = (short)f2bf_u(OB1[r] * linvB);
    }
  }
}

// ---------------- Output proj GEMM + bias + residual (fp32 out) -----------
// 128x128 tile, BK=32, 2-PHASE double-buffered staging (compile-time buffer
// index, hoisted bases, vmcnt(4), no setprio - the R18-proven qkv pattern);
// XCD-aware swizzle; chunk-XOR fragment reads match pre-swizzled cb/wb.
__global__ __launch_bounds__(256) void proj_gemm(
    const short* __restrict__ cb, const short* __restrict__ wo,
    const float* __restrict__ bo, const float* __restrict__ x,
    float* __restrict__ out) {
  int lid = blockIdx.x + (blockIdx.y << 3);   // grid = dim3(8,64)
  int xcd = lid & 7;
  int tt = lid >> 3;           // 0..63
  int m0 = (xcd * 8 + (tt >> 3)) * 128;
  int n0 = (tt & 7) * 128;

  __shared__ alignas(16) short smem[2 * 8192];

  int t = threadIdx.x;
  int l = t & 63, w = t >> 6;
  int wm = w >> 1, wn = w & 1;
  int srow = l >> 2, scol = (l & 3) * 8;
  int fr = l & 15, fg = l >> 4;
  int pl = (fr & 3) ^ ((fr >> 2) & 3);
  int cA = ((fg ^ pl) << 3);

  int r0a = (w * 2 + 0) * 16;
  int r0b = (w * 2 + 1) * 16;
  const short* gA0 = cb + (size_t)(m0 + r0a + srow) * Dx + scol;
  const short* gA1 = cb + (size_t)(m0 + r0b + srow) * Dx + scol;
  const short* gB0 = wo + (size_t)(n0 + r0a + srow) * Dx + scol;
  const short* gB1 = wo + (size_t)(n0 + r0b + srow) * Dx + scol;

  f32x4 acc[4][4] = {};

#define PSTAGE(step, bf) do {                                             \
    size_t ko = (size_t)(step) * 32;                                      \
    GLDS16(gA0 + ko, &smem[(bf) * 8192 + r0a * 32]);                      \
    GLDS16(gB0 + ko, &smem[(bf) * 8192 + 4096 + r0a * 32]);               \
    GLDS16(gA1 + ko, &smem[(bf) * 8192 + r0b * 32]);                      \
    GLDS16(gB1 + ko, &smem[(bf) * 8192 + 4096 + r0b * 32]);               \
  } while (0)

#define PBODY(step, cur) do {                                             \
    if ((step) < 31) {                                                    \
      PSTAGE((step) + 1, (cur) ^ 1);                                      \
      asm volatile("s_waitcnt vmcnt(4)" ::: "memory");                    \
    } else {                                                              \
      asm volatile("s_waitcnt vmcnt(0)" ::: "memory");                    \
    }                                                                     \
    __builtin_amdgcn_s_barrier();                                         \
    const short* Al = &smem[(cur) * 8192];                                \
    const short* Bl = &smem[(cur) * 8192 + 4096];                         \
    bf16x8 af[4], bfm[4];                                                 \
    _Pragma("unroll")                                                     \
    for (int i = 0; i < 4; ++i)                                           \
      af[i] = *(const bf16x8*)&Al[(wm * 64 + i * 16 + fr) * 32 + cA];     \
    _Pragma("unroll")                                                     \
    for (int i = 0; i < 4; ++i)                                           \
      bfm[i] = *(const bf16x8*)&Bl[(wn * 64 + i * 16 + fr) * 32 + cA];    \
    _Pragma("unroll")                                                     \
    for (int mi = 0; mi < 4; ++mi)                                        \
      _Pragma("unroll")                                                   \
      for (int ni = 0; ni < 4; ++ni)                                      \
        acc[mi][ni] = __builtin_amdgcn_mfma_f32_16x16x32_bf16(            \
            af[mi], bfm[ni], acc[mi][ni], 0, 0, 0);                       \
    __builtin_amdgcn_s_barrier();                                         \
  } while (0)

  PSTAGE(0, 0);

  for (int ks = 0; ks < 32; ks += 2) {
    PBODY(ks, 0);
    PBODY(ks + 1, 1);
  }
#undef PBODY
#undef PSTAGE

#pragma unroll
  for (int ni = 0; ni < 4; ++ni) {
    int n = n0 + wn * 64 + ni * 16 + fr;
    float bias_n = bo[n];
#pragma unroll
    for (int mi = 0; mi < 4; ++mi) {
#pragma unroll
      for (int r = 0; r < 4; ++r) {
        int m = m0 + wm * 64 + mi * 16 + fg * 4 + r;
        float y = acc[mi][ni][r] + bias_n + x[(size_t)m * Dx + n];
        out[(size_t)m * Dx + n] = y;
      }
    }
  }
}

// ---------------- LayerNorm (in-place on fp32 rows of 1024) ---------------
__global__ __launch_bounds__(256) void ln_kernel(float* __restrict__ io,
                                                 const float* __restrict__ lw,
                                                 const float* __restrict__ lb) {
  int row = blockIdx.x;
  float* p = io + (size_t)row * Dx;
  int c = threadIdx.x * 4;
  float4 v = *(float4*)&p[c];
  float s = v.x + v.y + v.z + v.w;
  float q = v.x * v.x + v.y * v.y + v.z * v.z + v.w * v.w;
#pragma unroll
  for (int d = 1; d < 64; d <<= 1) {
    s += __shfl_xor(s, d, 64);
    q += __shfl_xor(q, d, 64);
  }
  __shared__ float ss[4], qq[4];
  int l = threadIdx.x & 63, w = threadIdx.x >> 6;
  if (l == 0) { ss[w] = s; qq[w] = q; }
  __syncthreads();
  s = ss[0] + ss[1] + ss[2] + ss[3];
  q = qq[0] + qq[1] + qq[2] + qq[3];
  float mu = s * (1.f / Dx);
  float var = q * (1.f / Dx) - mu * mu;
  float rstd = rsqrtf(var + 1e-5f);
  float4 w4 = *(const float4*)&lw[c];
  float4 b4 = *(const float4*)&lb[c];
  float4 o;
  o.x = (v.x - mu) * rstd * w4.x + b4.x;
  o.y = (v.y - mu) * rstd * w4.y + b4.y;
  o.z = (v.z - mu) * rstd * w4.z + b4.z;
  o.w = (v.w - mu) * rstd * w4.w + b4.w;
  *(float4*)&p[c] = o;
}

// ---------------- launch ----------------
extern "C" void kernel_launch(void* const* d_in, const int* in_sizes, int n_in,
                              void* d_out, int out_size, void* d_ws, size_t ws_size,
                              hipStream_t stream) {
  const float* x   = (const float*)d_in[0];
  const int*   msk = (const int*)d_in[1];
  const float* Wq  = (const float*)d_in[2];
  const float* bq  = (const float*)d_in[3];
  const float* Wk  = (const float*)d_in[4];
  const float* bk  = (const float*)d_in[5];
  const float* Wv  = (const float*)d_in[6];
  const float* bv  = (const float*)d_in[7];
  const float* Wo  = (const float*)d_in[8];
  const float* bo  = (const float*)d_in[9];
  const float* lnw = (const float*)d_in[10];
  const float* lnb = (const float*)d_in[11];
  float* out = (float*)d_out;

  // Workspace layout (88 MB total)
  char* ws = (char*)d_ws;
  short* xb = (short*)(ws);                          // 16 MB  bf16 x (chunk-swz)
  short* wb = (short*)(ws + (size_t)(16 << 20));     //  8 MB  bf16 W (chunk-swz)
  short* qb = (short*)(ws + (size_t)(24 << 20));     // 16 MB  bf16 Q (pre-scaled)
  short* kb = (short*)(ws + (size_t)(40 << 20));     // 16 MB  bf16 K swizzled
  short* vb = (short*)(ws + (size_t)(56 << 20));     // 16 MB  bf16 V^T swizzled
  short* cb = (short*)(ws + (size_t)(72 << 20));     // 16 MB  bf16 ctx (chunk-swz)
  float* madd = out;                        // d_out scratch, overwritten by proj
  unsigned* mbits = (unsigned*)(out + Mx);  // 4 uints after madd

  prep_kernel<<<6180, 256, 0, stream>>>(x, Wq, Wk, Wv, Wo, msk,
                                        (uint4*)xb, (uint4*)wb, madd, mbits);
  qkv_gemm<<<dim3(8, 64, 3), 256, 0, stream>>>(xb, wb, bq, bk, bv, qb, kb, vb);
  attn_kernel<<<dim3(64, 8), 256, 0, stream>>>(qb, kb, vb, madd, mbits, cb);
  proj_gemm<<<dim3(8, 64), 256, 0, stream>>>(cb, wb + 3 * (size_t)(Dx * Dx), bo, x, out);
  ln_kernel<<<Mx, 256, 0, stream>>>(out, lnw, lnb);
}

// Round 21
// 194.403 us; speedup vs baseline: 1.0965x; 1.0049x over previous
//
#include <hip/hip_runtime.h>
#include <hip/hip_bf16.h>
#include <stdint.h>

// Problem constants
#define Bx  4
#define Sx  2048
#define Dx  1024
#define Hx  16
#define DHx 64
#define Mx  (Bx*Sx)   // 8192

typedef short bf16x8 __attribute__((ext_vector_type(8)));
typedef float f32x4  __attribute__((ext_vector_type(4)));
typedef float f32x16 __attribute__((ext_vector_type(16)));

#define C1 0.18033688f   // 0.125 * log2(e)

__device__ __forceinline__ unsigned short f2bf_u(float f) {
  union { float f; unsigned int u; } c; c.f = f;
  return (unsigned short)((c.u + 0x7fffu + ((c.u >> 16) & 1u)) >> 16);
}
__device__ __forceinline__ unsigned int pack2(float lo, float hi) {
  return ((unsigned int)f2bf_u(hi) << 16) | (unsigned int)f2bf_u(lo);
}
// packed f32->bf16 (RNE), lo -> bits[15:0], hi -> bits[31:16]
__device__ __forceinline__ unsigned int cvtpk(float lo_, float hi_) {
  unsigned int r;
  asm("v_cvt_pk_bf16_f32 %0, %1, %2" : "=v"(r) : "v"(lo_), "v"(hi_));
  return r;
}
// swap low 32 lanes of d with high 32 lanes of s
__device__ __forceinline__ void swap32(unsigned int& d, unsigned int& s) {
  asm("v_permlane32_swap_b32 %0, %1" : "+v"(d), "+v"(s));
}

#define GLDS16(gp, lp) __builtin_amdgcn_global_load_lds( \
  (const __attribute__((address_space(1))) unsigned int*)(gp), \
  (__attribute__((address_space(3))) unsigned int*)(lp), 16, 0, 0)

// ---------------- fused prep: cvt x + 4 weights, madd, maskbits ----------
// grid layout: [0,4096) x-cvt | [4096,6144) W-cvt (512 blocks each) |
//              [6144,6176) madd | [6176,6180) maskbits
// xb/wb stored CHUNK-SWIZZLED: c ^= P(row), P(row)=(row&3)^((row>>2)&3).
__global__ __launch_bounds__(256) void prep_kernel(
    const float* __restrict__ x,  const float* __restrict__ Wq,
    const float* __restrict__ Wk, const float* __restrict__ Wv,
    const float* __restrict__ Wo, const int* __restrict__ mask,
    uint4* __restrict__ xb4, uint4* __restrict__ wb4,
    float* __restrict__ madd, unsigned* __restrict__ mb) {
  int bid = blockIdx.x, t = threadIdx.x;
  if (bid < 6144) {
    const float* src;
    uint4* dst;
    int i;
    if (bid < 4096) {
      src = x; dst = xb4; i = bid * 256 + t;
    } else {
      int wbid = bid - 4096;          // 0..2047
      int widx = wbid >> 9;           // 0..3
      src = (widx == 0) ? Wq : (widx == 1) ? Wk : (widx == 2) ? Wv : Wo;
      dst = wb4 + (size_t)widx * 131072;
      i = (wbid & 511) * 256 + t;
    }
    const float4* s = (const float4*)src + (size_t)i * 2;
    float4 a = s[0], b = s[1];
    uint4 o;
    o.x = pack2(a.x, a.y); o.y = pack2(a.z, a.w);
    o.z = pack2(b.x, b.y); o.w = pack2(b.z, b.w);
    int ip = (i & ~3) | ((i & 3) ^ ((i >> 7) & 3) ^ ((i >> 9) & 3));
    dst[ip] = o;
  } else if (bid < 6176) {
    int i = (bid - 6144) * 256 + t;   // 0..8191
    madd[i] = (mask[i] == 0) ? -1e30f : 0.0f;
  } else {
    int b = bid - 6176;               // 0..3
    if (t < 64) {
      int any = 0;
      if (t < 32) {
        for (int i = 0; i < 64; ++i) any |= (mask[b * Sx + t * 64 + i] == 0);
      }
      unsigned long long bits = __ballot(any != 0);
      if (t == 0) mb[b] = (unsigned)bits;
    }
  }
}

// ---------------- QKV GEMM: y = x @ W^T + b ----
// 128x128 tile, BK=32, 4 waves. 3-BUFFER DEPTH-2 pipelined global_load_lds
// staging (WIN R20: 79 -> ~72us): two stages in flight over each compute
// phase, vmcnt(8) waits only for the current buffer's 4 loads. Compile-time
// buffer indices via 3-periodic unroll; hoisted base pointers; NO setprio.
// XCD-aware swizzle: xcd = lid&7 owns m_tiles [xcd*8, xcd*8+8) x all n, per z.
// Fragment reads XOR chunk with pl=(fr&3)^((fr>>2)&3) (prep layout).
// Output layouts (per head, head base = (b*16+h)*S*64):
//  Q: normal [B,H,S,DH], PRE-SCALED by C1 (log2-domain scores)
//  K: tile-linear swizzled: elem (s,dh) at s*64 + (((dh>>3)^(s&7))<<3) + (dh&7)
//  V: transposed tile-linear swizzled (tiles of 64 s):
//     elem (s,dh) at (s>>6)*4096 + dh*64 + ((((s>>3)&7)^(dh&7))<<3) + (s&7)
__global__ __launch_bounds__(256) void qkv_gemm(
    const short* __restrict__ xb, const short* __restrict__ wb,
    const float* __restrict__ bq, const float* __restrict__ bk,
    const float* __restrict__ bv,
    short* __restrict__ qb, short* __restrict__ kb, short* __restrict__ vb) {
  // linear wg id (grid = dim3(8,64,3)); xcd = lid&7 by dispatch round-robin
  int lid = blockIdx.x + (blockIdx.y << 3) + (blockIdx.z << 9);
  int xcd = lid & 7;
  int idx = lid >> 3;          // 0..191
  int which = idx >> 6;        // 0..2
  int tt = idx & 63;           // 0..63
  int m0 = (xcd * 8 + (tt >> 3)) * 128;
  int n0 = (tt & 7) * 128;

  const short* Wm  = wb + (size_t)which * Dx * Dx;
  const float* bias = (which == 0) ? bq : (which == 1 ? bk : bv);

  // 3 staging buffers (3 x 8192 shorts = 48 KB); V epilogue reuses the
  // first 128*136 = 17408 shorts as a transpose buffer.
  __shared__ alignas(16) short smem[3 * 8192];

  int t = threadIdx.x;
  int l = t & 63, w = t >> 6;
  int wm = w >> 1, wn = w & 1;
  int srow = l >> 2;
  int scol = (l & 3) * 8;
  int fr = l & 15, fg = l >> 4;
  int pl = (fr & 3) ^ ((fr >> 2) & 3);     // chunk-XOR (matches prep layout)
  int cA = ((fg ^ pl) << 3);               // per-lane constant read chunk

  // Hoisted per-lane staging base pointers (k=0); step adds step*32 elems.
  int r0a = (w * 2 + 0) * 16;
  int r0b = (w * 2 + 1) * 16;
  const short* gA0 = xb + (size_t)(m0 + r0a + srow) * Dx + scol;
  const short* gA1 = xb + (size_t)(m0 + r0b + srow) * Dx + scol;
  const short* gB0 = Wm + (size_t)(n0 + r0a + srow) * Dx + scol;
  const short* gB1 = Wm + (size_t)(n0 + r0b + srow) * Dx + scol;

  f32x4 acc[4][4] = {};

#define QSTAGE(step, bf) do {                                             \
    size_t ko = (size_t)(step) * 32;                                      \
    GLDS16(gA0 + ko, &smem[(bf) * 8192 + r0a * 32]);                      \
    GLDS16(gB0 + ko, &smem[(bf) * 8192 + 4096 + r0a * 32]);               \
    GLDS16(gA1 + ko, &smem[(bf) * 8192 + r0b * 32]);                      \
    GLDS16(gB1 + ko, &smem[(bf) * 8192 + 4096 + r0b * 32]);               \
  } while (0)

// depth-2: at compute(step), stages step+1 and step+2 are in flight.
#define QBODY(step, cur, nbf) do {                                        \
    if ((step) < 30) {                                                    \
      QSTAGE((step) + 2, (nbf));                                          \
      asm volatile("s_waitcnt vmcnt(8)" ::: "memory");                    \
    } else if ((step) == 30) {                                            \
      asm volatile("s_waitcnt vmcnt(4)" ::: "memory");                    \
    } else {                                                              \
      asm volatile("s_waitcnt vmcnt(0)" ::: "memory");                    \
    }                                                                     \
    __builtin_amdgcn_s_barrier();                                         \
    const short* Al = &smem[(cur) * 8192];                                \
    const short* Bl = &smem[(cur) * 8192 + 4096];                         \
    bf16x8 af[4], bfm[4];                                                 \
    _Pragma("unroll")                                                     \
    for (int i = 0; i < 4; ++i)                                           \
      af[i] = *(const bf16x8*)&Al[(wm * 64 + i * 16 + fr) * 32 + cA];     \
    _Pragma("unroll")                                                     \
    for (int i = 0; i < 4; ++i)                                           \
      bfm[i] = *(const bf16x8*)&Bl[(wn * 64 + i * 16 + fr) * 32 + cA];    \
    _Pragma("unroll")                                                     \
    for (int mi = 0; mi < 4; ++mi)                                        \
      _Pragma("unroll")                                                   \
      for (int ni = 0; ni < 4; ++ni)                                      \
        acc[mi][ni] = __builtin_amdgcn_mfma_f32_16x16x32_bf16(            \
            af[mi], bfm[ni], acc[mi][ni], 0, 0, 0);                       \
    __builtin_amdgcn_s_barrier();                                         \
  } while (0)

  QSTAGE(0, 0);
  QSTAGE(1, 1);

  for (int ks = 0; ks < 30; ks += 3) {
    QBODY(ks,     0, 2);
    QBODY(ks + 1, 1, 0);
    QBODY(ks + 2, 2, 1);
  }
  QBODY(30, 0, 0);   // 30 % 3 == 0
  QBODY(31, 1, 0);   // 31 % 3 == 1
#undef QBODY
#undef QSTAGE

  if (which == 2) {
    // ---- V epilogue: bias, transpose via LDS, coalesced swizzled store ----
    __syncthreads();
#pragma unroll
    for (int ni = 0; ni < 4; ++ni) {
      int n_l = wn * 64 + ni * 16 + fr;
      float bias_n = bias[n0 + n_l];
#pragma unroll
      for (int mi = 0; mi < 4; ++mi)
#pragma unroll
        for (int r = 0; r < 4; ++r) {
          int m_l = wm * 64 + mi * 16 + fg * 4 + r;
          smem[n_l * 136 + m_l] = (short)f2bf_u(acc[mi][ni][r] + bias_n);
        }
    }
    __syncthreads();
    int b = m0 >> 11, s0_ = m0 & 2047;   // s0_ multiple of 128
#pragma unroll
    for (int it = 0; it < 8; ++it) {
      int idx2 = t + it * 256;          // 0..2047
      int n_l = idx2 >> 4, c = idx2 & 15;
      int4 v = *(const int4*)&smem[n_l * 136 + c * 8];
      int n = n0 + n_l, h = n >> 6, dh = n & 63;
      int chunk = (c & 7) ^ (dh & 7);
      size_t off = (size_t)(b * Hx + h) * Sx * 64
                 + (size_t)((s0_ >> 6) + (c >> 3)) * 4096
                 + dh * 64 + chunk * 8;
      *(int4*)&vb[off] = v;
    }
    return;
  }

#pragma unroll
  for (int ni = 0; ni < 4; ++ni) {
    int n = n0 + wn * 64 + ni * 16 + fr;
    int h = n >> 6, dh = n & 63;
    float bias_n = bias[n];
#pragma unroll
    for (int mi = 0; mi < 4; ++mi) {
#pragma unroll
      for (int r = 0; r < 4; ++r) {
        int m = m0 + wm * 64 + mi * 16 + fg * 4 + r;
        int b = m >> 11, s = m & 2047;
        float y = acc[mi][ni][r] + bias_n;
        size_t hb = (size_t)(b * Hx + h) * Sx * DHx;
        if (which == 0) {
          qb[hb + (size_t)s * DHx + dh] = (short)f2bf_u(y * C1);
        } else {
          kb[hb + (size_t)s * 64 + ((((dh >> 3) ^ (s & 7)) << 3) | (dh & 7))] =
              (short)f2bf_u(y);
        }
      }
    }
  }
}

// ---------------- Flash attention, swapped-QK 32x32, fixed-scale softmax ----
// grid: (bh=64, qt=8). block: 256 = 4 waves; wave owns 64 query rows as TWO
// 32-row groups (A/B) sharing every K/V LDS fragment read - halves LDS-pipe
// read traffic per q-row. KV tile = 64, double-buffered staging with counted
// vmcnt(4). __launch_bounds__(256,2). The ctx write applies the chunk-XOR
// P(row) so cb matches the GEMM pre-swizzled A-operand layout.
__global__ __launch_bounds__(256, 2) void attn_kernel(
    const short* __restrict__ qb, const short* __restrict__ kb,
    const short* __restrict__ vb, const float* __restrict__ madd,
    const unsigned* __restrict__ maskbits, short* __restrict__ cbuf) {
  int bh = blockIdx.x;   // 0..63 -> XCD = bh&7
  int qt = blockIdx.y;   // 0..7
  int b  = bh >> 4;

  __shared__ alignas(16) short Kl[2][4096];   // [64 s][64 dh] swizzled
  __shared__ alignas(16) short Vt[2][4096];   // [64 dh][64 s] swizzled

  int t = threadIdx.x, l = t & 63, w = t >> 6;
  int lo = l & 31, hi = l >> 5;

  // Q fragments (B-operand) for both q-groups: lane holds Q[q0+lo][...]
  const short* qgA = qb + ((size_t)bh * Sx + qt * 256 + w * 64 + lo) * 64;
  const short* qgB = qgA + 32 * 64;
  bf16x8 qfA[4], qfB[4];
#pragma unroll
  for (int ks = 0; ks < 4; ++ks) {
    qfA[ks] = *(const bf16x8*)&qgA[ks * 16 + hi * 8];
    qfB[ks] = *(const bf16x8*)&qgB[ks * 16 + hi * 8];
  }

  // Loop-invariant per-lane LDS fragment offsets (shorts). Same formula
  // serves K (QK phase) and V (PV phase).
  int koff[4], koff32[4];
#pragma unroll
  for (int ks = 0; ks < 4; ++ks) {
    int c = ((2 * ks + hi) ^ (lo & 7)) << 3;
    koff[ks]   = lo * 64 + c;
    koff32[ks] = (32 + lo) * 64 + c;
  }

  const short* kg = kb + (size_t)bh * Sx * 64;
  const short* vg = vb + (size_t)bh * Sx * 64;
  const float* mg = madd + b * Sx;
  unsigned mbits = maskbits[b];

  bf16x8 ones;
#pragma unroll
  for (int i = 0; i < 8; ++i) ones[i] = (short)0x3F80;

  f32x16 OA0 = {}, OA1 = {}, SsA = {};
  f32x16 OB0 = {}, OB1 = {}, SsB = {};

#define STAGE(tile, bf) do {                                              \
    const short* ks_ = kg + (size_t)(tile) * 4096;                        \
    const short* vs_ = vg + (size_t)(tile) * 4096;                        \
    GLDS16(ks_ + w * 512 + l * 8,        &Kl[bf][w * 512]);               \
    GLDS16(ks_ + 2048 + w * 512 + l * 8, &Kl[bf][2048 + w * 512]);        \
    GLDS16(vs_ + w * 512 + l * 8,        &Vt[bf][w * 512]);               \
    GLDS16(vs_ + 2048 + w * 512 + l * 8, &Vt[bf][2048 + w * 512]);        \
  } while (0)

#define TBODY(tile, cur) do {                                             \
    if ((tile) < 31) {                                                    \
      STAGE((tile) + 1, (cur) ^ 1);                                      \
      asm volatile("s_waitcnt vmcnt(4)" ::: "memory");                    \
    } else {                                                              \
      asm volatile("s_waitcnt vmcnt(0)" ::: "memory");                    \
    }                                                                     \
    __builtin_amdgcn_s_barrier();                                         \
    const short* Kb = &Kl[cur][0];                                        \
    const short* Vb = &Vt[cur][0];                                        \
    f32x16 sA0 = {}, sA1 = {}, sB0 = {}, sB1 = {};                        \
    __builtin_amdgcn_s_setprio(1);                                        \
    _Pragma("unroll")                                                     \
    for (int ks = 0; ks < 4; ++ks) {                                      \
      bf16x8 kf = *(const bf16x8*)&Kb[koff[ks]];                          \
      sA0 = __builtin_amdgcn_mfma_f32_32x32x16_bf16(kf, qfA[ks], sA0, 0, 0, 0); \
      sB0 = __builtin_amdgcn_mfma_f32_32x32x16_bf16(kf, qfB[ks], sB0, 0, 0, 0); \
    }                                                                     \
    _Pragma("unroll")                                                     \
    for (int ks = 0; ks < 4; ++ks) {                                      \
      bf16x8 kf = *(const bf16x8*)&Kb[koff32[ks]];                        \
      sA1 = __builtin_amdgcn_mfma_f32_32x32x16_bf16(kf, qfA[ks], sA1, 0, 0, 0); \
      sB1 = __builtin_amdgcn_mfma_f32_32x32x16_bf16(kf, qfB[ks], sB1, 0, 0, 0); \
    }                                                                     \
    __builtin_amdgcn_s_setprio(0);                                        \
    if ((mbits >> (tile)) & 1) {                                          \
      const float* mrow = mg + (tile) * 64;                               \
      _Pragma("unroll")                                                   \
      for (int r = 0; r < 16; ++r) {                                      \
        int key = (r & 3) + 8 * (r >> 2) + 4 * hi;                        \
        float m0_ = mrow[key], m1_ = mrow[32 + key];                      \
        sA0[r] += m0_; sA1[r] += m1_;                                     \
        sB0[r] += m0_; sB1[r] += m1_;                                     \
      }                                                                   \
    }                                                                     \
    _Pragma("unroll")                                                     \
    for (int r = 0; r < 16; ++r) {                                        \
      sA0[r] = __builtin_amdgcn_exp2f(sA0[r]);                            \
      sA1[r] = __builtin_amdgcn_exp2f(sA1[r]);                            \
      sB0[r] = __builtin_amdgcn_exp2f(sB0[r]);                            \
      sB1[r] = __builtin_amdgcn_exp2f(sB1[r]);                            \
    }                                                                     \
    __builtin_amdgcn_s_setprio(1);                                        \
    _Pragma("unroll")                                                     \
    for (int kbi = 0; kbi < 2; ++kbi) {                                   \
      _Pragma("unroll")                                                   \
      for (int half = 0; half < 2; ++half) {                              \
        int po = half * 8;                                                \
        unsigned int uA, uA2, vA, vA2, uB, uB2, vB, vB2;                  \
        if (kbi == 0) {                                                   \
          uA  = cvtpk(sA0[po + 0], sA0[po + 1]);                          \
          uA2 = cvtpk(sA0[po + 2], sA0[po + 3]);                          \
          vA  = cvtpk(sA0[po + 4], sA0[po + 5]);                          \
          vA2 = cvtpk(sA0[po + 6], sA0[po + 7]);                          \
          uB  = cvtpk(sB0[po + 0], sB0[po + 1]);                          \
          uB2 = cvtpk(sB0[po + 2], sB0[po + 3]);                          \
          vB  = cvtpk(sB0[po + 4], sB0[po + 5]);                          \
          vB2 = cvtpk(sB0[po + 6], sB0[po + 7]);                          \
        } else {                                                          \
          uA  = cvtpk(sA1[po + 0], sA1[po + 1]);                          \
          uA2 = cvtpk(sA1[po + 2], sA1[po + 3]);                          \
          vA  = cvtpk(sA1[po + 4], sA1[po + 5]);                          \
          vA2 = cvtpk(sA1[po + 6], sA1[po + 7]);                          \
          uB  = cvtpk(sB1[po + 0], sB1[po + 1]);                          \
          uB2 = cvtpk(sB1[po + 2], sB1[po + 3]);                          \
          vB  = cvtpk(sB1[po + 4], sB1[po + 5]);                          \
          vB2 = cvtpk(sB1[po + 6], sB1[po + 7]);                          \
        }                                                                 \
        swap32(vA, uA); swap32(vA2, uA2);                                 \
        swap32(vB, uB); swap32(vB2, uB2);                                 \
        union { unsigned int i[4]; bf16x8 v8; } puA, puB;                 \
        puA.i[0] = uA; puA.i[1] = uA2; puA.i[2] = vA; puA.i[3] = vA2;     \
        puB.i[0] = uB; puB.i[1] = uB2; puB.i[2] = vB; puB.i[3] = vB2;     \
        int vi = kbi * 2 + half;                                          \
        bf16x8 vf0 = *(const bf16x8*)&Vb[koff[vi]];                       \
        bf16x8 vf1 = *(const bf16x8*)&Vb[koff32[vi]];                     \
        OA0 = __builtin_amdgcn_mfma_f32_32x32x16_bf16(puA.v8, vf0, OA0, 0, 0, 0); \
        OA1 = __builtin_amdgcn_mfma_f32_32x32x16_bf16(puA.v8, vf1, OA1, 0, 0, 0); \
        SsA = __builtin_amdgcn_mfma_f32_32x32x16_bf16(puA.v8, ones, SsA, 0, 0, 0); \
        OB0 = __builtin_amdgcn_mfma_f32_32x32x16_bf16(puB.v8, vf0, OB0, 0, 0, 0); \
        OB1 = __builtin_amdgcn_mfma_f32_32x32x16_bf16(puB.v8, vf1, OB1, 0, 0, 0); \
        SsB = __builtin_amdgcn_mfma_f32_32x32x16_bf16(puB.v8, ones, SsB, 0, 0, 0); \
      }                                                                   \
    }                                                                     \
    __builtin_amdgcn_s_setprio(0);                                        \
    __builtin_amdgcn_s_barrier();                                        \
  } while (0)

  STAGE(0, 0);

  for (int tile = 0; tile < 32; tile += 2) {
    TBODY(tile, 0);
    TBODY(tile + 1, 1);
  }
#undef TBODY
#undef STAGE

  // ---- normalize + write ctx (chunk-swizzled cb for proj's A-operand) ----
  int h = bh & 15, bq_ = bh >> 4;
  int loLo = lo & 7, loCh = lo >> 3;   // chunk/offset of this lane's column
#pragma unroll
  for (int a = 0; a < 4; ++a) {
#pragma unroll
    for (int j = 0; j < 4; ++j) {
      int r = a * 4 + j;
      int srow = a * 8 + hi * 4 + j;
      int p = (srow & 3) ^ ((srow >> 2) & 3);   // P(row); rows sA,sB share it
      int colp = ((loCh ^ p) << 3) | loLo;      // permuted within 32-col block
      float linvA = __builtin_amdgcn_rcpf(SsA[r]);
      float linvB = __builtin_amdgcn_rcpf(SsB[r]);
      int sA = qt * 256 + w * 64 + srow;
      int sB = sA + 32;
      size_t rowbA = ((size_t)(bq_ * Sx + sA)) * Dx + h * 64;
      size_t rowbB = ((size_t)(bq_ * Sx + sB)) * Dx + h * 64;
      cbuf[rowbA + colp]      = (short)f2bf_u(OA0[r] * linvA);
      cbuf[rowbA + 32 + colp] = (short)f2bf_u(OA1[r] * linvA);
      cbuf[rowbB + colp]      = (short)f2bf_u(OB0[r] * linvB);
      cbuf[rowbB + 32 + colp] = (short)f2bf_u(OB1[r] * linvB);
    }
  }
}

// ---------------- Output proj GEMM + bias + residual (fp32 out) -----------
// 128x128 tile, BK=32, 3-BUFFER DEPTH-2 pipelined staging (the R20-proven
// qkv pattern: compile-time buffer indices, hoisted bases, vmcnt(8)/4/0,
// no setprio); XCD-aware swizzle; chunk-XOR reads match pre-swizzled cb/wb.
__global__ __launch_bounds__(256) void proj_gemm(
    const short* __restrict__ cb, const short* __restrict__ wo,
    const float* __restrict__ bo, const float* __restrict__ x,
    float* __restrict__ out) {
  int lid = blockIdx.x + (blockIdx.y << 3);   // grid = dim3(8,64)
  int xcd = lid & 7;
  int tt = lid >> 3;           // 0..63
  int m0 = (xcd * 8 + (tt >> 3)) * 128;
  int n0 = (tt & 7) * 128;

  __shared__ alignas(16) short smem[3 * 8192];

  int t = threadIdx.x;
  int l = t & 63, w = t >> 6;
  int wm = w >> 1, wn = w & 1;
  int srow = l >> 2, scol = (l & 3) * 8;
  int fr = l & 15, fg = l >> 4;
  int pl = (fr & 3) ^ ((fr >> 2) & 3);
  int cA = ((fg ^ pl) << 3);

  int r0a = (w * 2 + 0) * 16;
  int r0b = (w * 2 + 1) * 16;
  const short* gA0 = cb + (size_t)(m0 + r0a + srow) * Dx + scol;
  const short* gA1 = cb + (size_t)(m0 + r0b + srow) * Dx + scol;
  const short* gB0 = wo + (size_t)(n0 + r0a + srow) * Dx + scol;
  const short* gB1 = wo + (size_t)(n0 + r0b + srow) * Dx + scol;

  f32x4 acc[4][4] = {};

#define PSTAGE(step, bf) do {                                             \
    size_t ko = (size_t)(step) * 32;                                      \
    GLDS16(gA0 + ko, &smem[(bf) * 8192 + r0a * 32]);                      \
    GLDS16(gB0 + ko, &smem[(bf) * 8192 + 4096 + r0a * 32]);               \
    GLDS16(gA1 + ko, &smem[(bf) * 8192 + r0b * 32]);                      \
    GLDS16(gB1 + ko, &smem[(bf) * 8192 + 4096 + r0b * 32]);               \
  } while (0)

#define PBODY(step, cur, nbf) do {                                        \
    if ((step) < 30) {                                                    \
      PSTAGE((step) + 2, (nbf));                                          \
      asm volatile("s_waitcnt vmcnt(8)" ::: "memory");                    \
    } else if ((step) == 30) {                                            \
      asm volatile("s_waitcnt vmcnt(4)" ::: "memory");                    \
    } else {                                                              \
      asm volatile("s_waitcnt vmcnt(0)" ::: "memory");                    \
    }                                                                     \
    __builtin_amdgcn_s_barrier();                                         \
    const short* Al = &smem[(cur) * 8192];                                \
    const short* Bl = &smem[(cur) * 8192 + 4096];                         \
    bf16x8 af[4], bfm[4];                                                 \
    _Pragma("unroll")                                                     \
    for (int i = 0; i < 4; ++i)                                           \
      af[i] = *(const bf16x8*)&Al[(wm * 64 + i * 16 + fr) * 32 + cA];     \
    _Pragma("unroll")                                                     \
    for (int i = 0; i < 4; ++i)                                           \
      bfm[i] = *(const bf16x8*)&Bl[(wn * 64 + i * 16 + fr) * 32 + cA];    \
    _Pragma("unroll")                                                     \
    for (int mi = 0; mi < 4; ++mi)                                        \
      _Pragma("unroll")                                                   \
      for (int ni = 0; ni < 4; ++ni)                                      \
        acc[mi][ni] = __builtin_amdgcn_mfma_f32_16x16x32_bf16(            \
            af[mi], bfm[ni], acc[mi][ni], 0, 0, 0);                       \
    __builtin_amdgcn_s_barrier();                                         \
  } while (0)

  PSTAGE(0, 0);
  PSTAGE(1, 1);

  for (int ks = 0; ks < 30; ks += 3) {
    PBODY(ks,     0, 2);
    PBODY(ks + 1, 1, 0);
    PBODY(ks + 2, 2, 1);
  }
  PBODY(30, 0, 0);
  PBODY(31, 1, 0);
#undef PBODY
#undef PSTAGE

#pragma unroll
  for (int ni = 0; ni < 4; ++ni) {
    int n = n0 + wn * 64 + ni * 16 + fr;
    float bias_n = bo[n];
#pragma unroll
    for (int mi = 0; mi < 4; ++mi) {
#pragma unroll
      for (int r = 0; r < 4; ++r) {
        int m = m0 + wm * 64 + mi * 16 + fg * 4 + r;
        float y = acc[mi][ni][r] + bias_n + x[(size_t)m * Dx + n];
        out[(size_t)m * Dx + n] = y;
      }
    }
  }
}

// ---------------- LayerNorm (in-place on fp32 rows of 1024) ---------------
__global__ __launch_bounds__(256) void ln_kernel(float* __restrict__ io,
                                                 const float* __restrict__ lw,
                                                 const float* __restrict__ lb) {
  int row = blockIdx.x;
  float* p = io + (size_t)row * Dx;
  int c = threadIdx.x * 4;
  float4 v = *(float4*)&p[c];
  float s = v.x + v.y + v.z + v.w;
  float q = v.x * v.x + v.y * v.y + v.z * v.z + v.w * v.w;
#pragma unroll
  for (int d = 1; d < 64; d <<= 1) {
    s += __shfl_xor(s, d, 64);
    q += __shfl_xor(q, d, 64);
  }
  __shared__ float ss[4], qq[4];
  int l = threadIdx.x & 63, w = threadIdx.x >> 6;
  if (l == 0) { ss[w] = s; qq[w] = q; }
  __syncthreads();
  s = ss[0] + ss[1] + ss[2] + ss[3];
  q = qq[0] + qq[1] + qq[2] + qq[3];
  float mu = s * (1.f / Dx);
  float var = q * (1.f / Dx) - mu * mu;
  float rstd = rsqrtf(var + 1e-5f);
  float4 w4 = *(const float4*)&lw[c];
  float4 b4 = *(const float4*)&lb[c];
  float4 o;
  o.x = (v.x - mu) * rstd * w4.x + b4.x;
  o.y = (v.y - mu) * rstd * w4.y + b4.y;
  o.z = (v.z - mu) * rstd * w4.z + b4.z;
  o.w = (v.w - mu) * rstd * w4.w + b4.w;
  *(float4*)&p[c] = o;
}

// ---------------- launch ----------------
extern "C" void kernel_launch(void* const* d_in, const int* in_sizes, int n_in,
                              void* d_out, int out_size, void* d_ws, size_t ws_size,
                              hipStream_t stream) {
  const float* x   = (const float*)d_in[0];
  const int*   msk = (const int*)d_in[1];
  const float* Wq  = (const float*)d_in[2];
  const float* bq  = (const float*)d_in[3];
  const float* Wk  = (const float*)d_in[4];
  const float* bk  = (const float*)d_in[5];
  const float* Wv  = (const float*)d_in[6];
  const float* bv  = (const float*)d_in[7];
  const float* Wo  = (const float*)d_in[8];
  const float* bo  = (const float*)d_in[9];
  const float* lnw = (const float*)d_in[10];
  const float* lnb = (const float*)d_in[11];
  float* out = (float*)d_out;

  // Workspace layout (88 MB total)
  char* ws = (char*)d_ws;
  short* xb = (short*)(ws);                          // 16 MB  bf16 x (chunk-swz)
  short* wb = (short*)(ws + (size_t)(16 << 20));     //  8 MB  bf16 W (chunk-swz)
  short* qb = (short*)(ws + (size_t)(24 << 20));     // 16 MB  bf16 Q (pre-scaled)
  short* kb = (short*)(ws + (size_t)(40 << 20));     // 16 MB  bf16 K swizzled
  short* vb = (short*)(ws + (size_t)(56 << 20));     // 16 MB  bf16 V^T swizzled
  short* cb = (short*)(ws + (size_t)(72 << 20));     // 16 MB  bf16 ctx (chunk-swz)
  float* madd = out;                        // d_out scratch, overwritten by proj
  unsigned* mbits = (unsigned*)(out + Mx);  // 4 uints after madd

  prep_kernel<<<6180, 256, 0, stream>>>(x, Wq, Wk, Wv, Wo, msk,
                                        (uint4*)xb, (uint4*)wb, madd, mbits);
  qkv_gemm<<<dim3(8, 64, 3), 256, 0, stream>>>(xb, wb, bq, bk, bv, qb, kb, vb);
  attn_kernel<<<dim3(64, 8), 256, 0, stream>>>(qb, kb, vb, madd, mbits, cb);
  proj_gemm<<<dim3(8, 64), 256, 0, stream>>>(cb, wb + 3 * (size_t)(Dx * Dx), bo, x, out);
  ln_kernel<<<Mx, 256, 0, stream>>>(out, lnw, lnb);
}